// Round 6
// baseline (219.151 us; speedup 1.0000x reference)
//
#include <hip/hip_runtime.h>
#include <hip/hip_bf16.h>

// GraphConv x3 + ReLU + log_softmax on MI355X — bf16/MFMA pipeline.
// Per layer: [T|S] = H @ [Wr|Ws] via mfma_f32_16x16x32_bf16, then atomic-free
// aggregation (bf16 gather, fp32 accum): H' = relu(sum_j T[esrc[j]] + br + S).
// Layer 3 fuses log_softmax (8-lane shuffle groups), fp32 out.
// R10: K-SPLIT mm staging — K=128 as 2x64 halves; (256,3) bounds.
// R11 (FAILED +6): place as TRAILING blocks of mm1 — trailing phase ran
//      after mm at 3 blocks/CU (inherited LDS+bounds) = latency kernel
//      with no TLP.
// R12 (NEUTRAL): deg line-spread — atomic line contention was a phantom.
// R13/R14 (NEUTRAL/REGR +56): L2-residency attempts for the T gather are
//      structurally impossible (no split fits 4MB at >=128B/edge); NT 2B
//      stores bypass write-combining.
// R15 (WIN 212->205.8): mm epilogue via swizzled-LDS transpose -> 16B
//      coalesced stores. Mechanism confirmed: partial-line global writes
//      cost ~2x nominal bytes.
// R16: place folded into mm1 as a PER-BLOCK PROLOGUE (block bid places
//      edges [bid*1024, +1024), 4/thread, BEFORE its mm tile). All 626
//      blocks co-resident (768 cap) -> atomics issued up front, latency
//      hidden under mm staging/MFMA; avoids R11's trailing-phase trap.
//      Removes the place launch + one gap. Diagnostic design: big drop =>
//      place was the ~20-35us pole; ~neutral => place small, pivot to
//      aggregate gather bytes.

#define N_NODES 40000
#define N_EDGES 640000
#define PAD_NODES 40064        // 313 * 128
#define DEG_CAP   40960        // int4-aligned >= N_NODES
#define ROW_CAP   64           // esrc slots per node

typedef float v4f __attribute__((ext_vector_type(4)));
typedef float v2f __attribute__((ext_vector_type(2)));
typedef short short8 __attribute__((ext_vector_type(8)));

__device__ inline unsigned short f2b(float f) {  // RNE fp32->bf16
    unsigned u = __float_as_uint(f);
    return (unsigned short)((u + 0x7fffu + ((u >> 16) & 1u)) >> 16);
}

// ---------------------------------------------------------------- prep
// deg zero + W transpose+cast to bf16.
__global__ __launch_bounds__(256) void prep_kernel(const float* __restrict__ Wr0, const float* __restrict__ Ws0,
                                                   const float* __restrict__ Wr1, const float* __restrict__ Ws1,
                                                   const float* __restrict__ Wr2, const float* __restrict__ Ws2,
                                                   unsigned short* __restrict__ Wt0,
                                                   unsigned short* __restrict__ Wt1,
                                                   unsigned short* __restrict__ Wt2,
                                                   int* __restrict__ deg) {
    int tid = blockIdx.x * 256 + threadIdx.x;
    if (tid < DEG_CAP / 4) {
        ((int4*)deg)[tid] = make_int4(0, 0, 0, 0);
    } else {
        int t = tid - DEG_CAP / 4;
        if (t < 32768) {
            int n = t >> 7, k = t & 127;
            const float* W = (n < 128) ? Wr0 : Ws0;
            Wt0[t] = f2b(W[k * 128 + (n & 127)]);
        } else if (t < 65536) {
            int u = t - 32768;
            int n = u >> 7, k = u & 127;
            const float* W = (n < 128) ? Wr1 : Ws1;
            Wt1[u] = f2b(W[k * 128 + (n & 127)]);
        } else if (t < 81920) {
            int u = t - 65536;
            int n = u >> 7, k = u & 127;
            const float* W = (n < 64) ? Wr2 : Ws2;
            Wt2[u] = f2b(W[k * 64 + (n & 63)]);
        }
    }
}

// ---------------------------------------------------------------- MFMA matmul
// A: [PAD_NODES][128] (bf16, or fp32 when F32 — converted during staging).
// Wt: [2*DO][128] bf16 pre-transposed. Block 256 thr = 4 waves, tile 128x128.
// K staged in 2 halves of 64. 3 blocks/CU co-residency.
// PLACE: block bid places edges [bid*1024, +1024) (4/thread) as a prologue
//        (R16). Independent atomics issued up front; latency hides under
//        staging/MFMA of co-resident waves.
// Epilogue (R15): swizzled LDS transpose -> 16B coalesced stores; zeros at
// node == N_NODES (the aggregate's dummy/pad row).
template <int DO, bool F32, bool PLACE>
__global__ __launch_bounds__(256, 3) void mm_kernel(const void* __restrict__ Ain,
                                                    const unsigned short* __restrict__ Wt,
                                                    unsigned short* __restrict__ T,
                                                    unsigned short* __restrict__ S,
                                                    const int* __restrict__ src,
                                                    const int* __restrict__ dst,
                                                    int* __restrict__ deg,
                                                    int* __restrict__ esrc) {
    __shared__ unsigned short Smem[128 * 128];   // 32 KB: staging + epilogue
    unsigned short* As = Smem;                   // [128][64] K-half
    unsigned short* Bs = Smem + 128 * 64;        // [128][64]

    const int tid = threadIdx.x;
    const int m0  = blockIdx.x * 128;
    const int n0  = blockIdx.y * 128;

    if (PLACE) {
        const int bid = blockIdx.y * gridDim.x + blockIdx.x;
        const int e0  = bid * 1024 + tid;
        if (e0 < N_EDGES) {                      // 625 blocks x 1024 edges
#pragma unroll
            for (int i = 0; i < 4; i++) {
                const int e = e0 + i * 256;
                const int d = dst[e];
                const int r = atomicAdd(&deg[d], 1);
                if (r < ROW_CAP) esrc[(size_t)d * ROW_CAP + r] = src[e];
            }
        }
    }

    const int wave = tid >> 6;
    const int lane = tid & 63;
    const int wr   = (wave >> 1) * 64;
    const int wc   = (wave & 1) * 64;
    const int qm   = lane & 15;
    const int k8   = (lane >> 4) * 8;

    v4f acc[4][4];
#pragma unroll
    for (int i = 0; i < 4; i++)
#pragma unroll
        for (int j = 0; j < 4; j++) acc[i][j] = (v4f)(0.0f);

#pragma unroll
    for (int half = 0; half < 2; half++) {
        // ---- stage A half: 128 rows x 64 k
        if (F32) {
            const float4* Xg = (const float4*)Ain;   // row pitch = 32 float4
#pragma unroll
            for (int i = 0; i < 8; i++) {
                int idx = i * 256 + tid;             // 0..2047 (float4 slots)
                int row = idx >> 4, c4 = idx & 15;   // 16 float4 per row-half
                int gr = m0 + row;
                if (gr > N_NODES - 1) gr = N_NODES - 1;  // pad tile: clamp
                float4 v = Xg[(size_t)gr * 32 + half * 16 + c4];
                uint2 p;
                p.x = (unsigned)f2b(v.x) | ((unsigned)f2b(v.y) << 16);
                p.y = (unsigned)f2b(v.z) | ((unsigned)f2b(v.w) << 16);
                ((uint2*)As)[idx] = p;
            }
        } else {
            const unsigned short* Ab = (const unsigned short*)Ain;
#pragma unroll
            for (int i = 0; i < 4; i++) {
                int idx = i * 256 + tid;             // 0..1023 (uint4 slots)
                int row = idx >> 3, c8 = idx & 7;    // 8 uint4 per row-half
                ((uint4*)As)[idx] =
                    *(const uint4*)(Ab + (size_t)(m0 + row) * 128 + half * 64 + c8 * 8);
            }
        }
        // ---- stage B half: Wt rows n0..n0+127, k-half
        {
#pragma unroll
            for (int i = 0; i < 4; i++) {
                int idx = i * 256 + tid;
                int row = idx >> 3, c8 = idx & 7;
                ((uint4*)Bs)[idx] =
                    *(const uint4*)(Wt + (size_t)(n0 + row) * 128 + half * 64 + c8 * 8);
            }
        }
        __syncthreads();

#pragma unroll
        for (int ks = 0; ks < 2; ks++) {
            short8 af[4], bf[4];
#pragma unroll
            for (int i = 0; i < 4; i++) {
                af[i] = *(const short8*)(const void*)(As + (wr + i * 16 + qm) * 64 + ks * 32 + k8);
                bf[i] = *(const short8*)(const void*)(Bs + (wc + i * 16 + qm) * 64 + ks * 32 + k8);
            }
#pragma unroll
            for (int mi = 0; mi < 4; mi++)
#pragma unroll
                for (int ni = 0; ni < 4; ni++)
                    acc[mi][ni] = __builtin_amdgcn_mfma_f32_16x16x32_bf16(af[mi], bf[ni], acc[mi][ni], 0, 0, 0);
        }
        __syncthreads();
    }

    // ---- R15 epilogue: swizzled LDS transpose -> 16B coalesced stores.
    // C/D layout: col=lane&15, row=(lane>>4)*4+reg  [m89-verified]
#pragma unroll
    for (int mi = 0; mi < 4; mi++) {
        const int rowBase = wr + mi * 16 + ((lane >> 4) << 2);
#pragma unroll
        for (int r = 0; r < 4; r++) {
            const int row = rowBase + r;
            const int sw  = ((row >> 2) & 3) << 4;
#pragma unroll
            for (int ni = 0; ni < 4; ni++) {
                const int c = wc + ni * 16 + qm;
                Smem[row * 128 + (c ^ sw)] = f2b(acc[mi][ni][r]);
            }
        }
    }
    __syncthreads();

    // node == N_NODES -> write ZEROS (dummy row read by aggregate pad slots).
#pragma unroll
    for (int i = 0; i < 8; i++) {
        const int chunk = i * 256 + tid;     // 2048 x 16B chunks = 32 KB tile
        const int row   = chunk >> 4;
        const int c0    = (chunk & 15) * 8;  // col start (8 ushorts = 16 B)
        const int sw    = ((row >> 2) & 3) << 4;
        const int node  = m0 + row;
        if (node <= N_NODES) {
            uint4 v = make_uint4(0, 0, 0, 0);
            if (node < N_NODES)
                v = *(const uint4*)(Smem + row * 128 + (c0 ^ sw));
            if (DO == 128) {
                *(uint4*)((n0 ? S : T) + (size_t)node * 128 + c0) = v;
            } else {
                if (c0 < 64) *(uint4*)(T + (size_t)node * 64 + c0) = v;
                else         *(uint4*)(S + (size_t)node * 64 + (c0 - 64)) = v;
            }
        }
    }
}

// ---------------------------------------------------------------- aggregate
// H[n] = relu(sum_j T[esrc[n*64+j]] + br + S[n]); bf16 in, fp32 accum.
// TPN = DO/8 threads/node, 8 dims each. 8-wide unrolled; pad slots masked
// in-register to dummy node 40000 (zero row). v2f acc for v_pk_add_f32.
__device__ inline void addp(v2f* a, uint4 q) {
    v2f t0 = { __uint_as_float(q.x << 16), __uint_as_float(q.x & 0xffff0000u) };
    v2f t1 = { __uint_as_float(q.y << 16), __uint_as_float(q.y & 0xffff0000u) };
    v2f t2 = { __uint_as_float(q.z << 16), __uint_as_float(q.z & 0xffff0000u) };
    v2f t3 = { __uint_as_float(q.w << 16), __uint_as_float(q.w & 0xffff0000u) };
    a[0] += t0; a[1] += t1; a[2] += t2; a[3] += t3;
}

template <int DO, bool LAST>
__global__ __launch_bounds__(256) void aggregate_kernel(const unsigned short* __restrict__ T,
                                                        const unsigned short* __restrict__ S,
                                                        const float* __restrict__ br,
                                                        const int* __restrict__ deg,
                                                        const int* __restrict__ esrc,
                                                        unsigned short* __restrict__ Hout,
                                                        float* __restrict__ Fout) {
    constexpr int TPN = DO / 8;        // 16 (DO=128) or 8 (DO=64)
    constexpr int G   = 256 / TPN;     // nodes per block
    const int lane = threadIdx.x % TPN;
    const int n    = blockIdx.x * G + threadIdx.x / TPN;

    int cnt = deg[n];
    if (cnt > ROW_CAP) cnt = ROW_CAP;  // safety (never expected)
    const int* erow = esrc + (size_t)n * ROW_CAP;
    const uint4* T4 = (const uint4*)T;

    const uint4  sv = ((const uint4*)S)[(size_t)n * TPN + lane];
    const float4 b0 = ((const float4*)br)[lane * 2];
    const float4 b1 = ((const float4*)br)[lane * 2 + 1];

    v2f acc[4];
    acc[0] = (v2f)(0.0f); acc[1] = (v2f)(0.0f);
    acc[2] = (v2f)(0.0f); acc[3] = (v2f)(0.0f);

    for (int o = 0; o < cnt; o += 8) {
        int4 i0 = *(const int4*)(erow + o);
        int4 i1 = *(const int4*)(erow + o + 4);
        // mask pad slots (uninitialized) -> dummy zero row (safe addressing)
        i0.x = (o + 0 < cnt) ? i0.x : N_NODES;
        i0.y = (o + 1 < cnt) ? i0.y : N_NODES;
        i0.z = (o + 2 < cnt) ? i0.z : N_NODES;
        i0.w = (o + 3 < cnt) ? i0.w : N_NODES;
        i1.x = (o + 4 < cnt) ? i1.x : N_NODES;
        i1.y = (o + 5 < cnt) ? i1.y : N_NODES;
        i1.z = (o + 6 < cnt) ? i1.z : N_NODES;
        i1.w = (o + 7 < cnt) ? i1.w : N_NODES;
        uint4 q0 = T4[(size_t)i0.x * TPN + lane];
        uint4 q1 = T4[(size_t)i0.y * TPN + lane];
        uint4 q2 = T4[(size_t)i0.z * TPN + lane];
        uint4 q3 = T4[(size_t)i0.w * TPN + lane];
        uint4 q4 = T4[(size_t)i1.x * TPN + lane];
        uint4 q5 = T4[(size_t)i1.y * TPN + lane];
        uint4 q6 = T4[(size_t)i1.z * TPN + lane];
        uint4 q7 = T4[(size_t)i1.w * TPN + lane];
        addp(acc, q0); addp(acc, q1); addp(acc, q2); addp(acc, q3);
        addp(acc, q4); addp(acc, q5); addp(acc, q6); addp(acc, q7);
    }
    addp(acc, sv);  // root term

    float v[8];
    v[0] = fmaxf(acc[0].x + b0.x, 0.f); v[1] = fmaxf(acc[0].y + b0.y, 0.f);
    v[2] = fmaxf(acc[1].x + b0.z, 0.f); v[3] = fmaxf(acc[1].y + b0.w, 0.f);
    v[4] = fmaxf(acc[2].x + b1.x, 0.f); v[5] = fmaxf(acc[2].y + b1.y, 0.f);
    v[6] = fmaxf(acc[3].x + b1.z, 0.f); v[7] = fmaxf(acc[3].y + b1.w, 0.f);

    if (LAST) {
        // DO=64, TPN=8: 8-lane shuffle groups; log_softmax
        float m = v[0];
#pragma unroll
        for (int i = 1; i < 8; i++) m = fmaxf(m, v[i]);
#pragma unroll
        for (int off = 4; off; off >>= 1) m = fmaxf(m, __shfl_xor(m, off, 64));
        float es = 0.f;
#pragma unroll
        for (int i = 0; i < 8; i++) es += expf(v[i] - m);
#pragma unroll
        for (int off = 4; off; off >>= 1) es += __shfl_xor(es, off, 64);
        float lse = m + logf(es);
        float4 o0 = make_float4(v[0] - lse, v[1] - lse, v[2] - lse, v[3] - lse);
        float4 o1 = make_float4(v[4] - lse, v[5] - lse, v[6] - lse, v[7] - lse);
        ((float4*)Fout)[(size_t)n * 16 + lane * 2]     = o0;
        ((float4*)Fout)[(size_t)n * 16 + lane * 2 + 1] = o1;
    } else {
        uint4 o;
        o.x = (unsigned)f2b(v[0]) | ((unsigned)f2b(v[1]) << 16);
        o.y = (unsigned)f2b(v[2]) | ((unsigned)f2b(v[3]) << 16);
        o.z = (unsigned)f2b(v[4]) | ((unsigned)f2b(v[5]) << 16);
        o.w = (unsigned)f2b(v[6]) | ((unsigned)f2b(v[7]) << 16);
        ((uint4*)Hout)[(size_t)n * TPN + lane] = o;
    }
}

// ---------------------------------------------------------------- launch

extern "C" void kernel_launch(void* const* d_in, const int* in_sizes, int n_in,
                              void* d_out, int out_size, void* d_ws, size_t ws_size,
                              hipStream_t stream) {
    const float* x    = (const float*)d_in[0];
    const int*   eidx = (const int*)d_in[1];   // [2, E] int32
    const float* Wr0  = (const float*)d_in[2];
    const float* br0  = (const float*)d_in[3];
    const float* Ws0  = (const float*)d_in[4];
    const float* Wr1  = (const float*)d_in[5];
    const float* br1  = (const float*)d_in[6];
    const float* Ws1  = (const float*)d_in[7];
    const float* Wr2  = (const float*)d_in[8];
    const float* br2  = (const float*)d_in[9];
    const float* Ws2  = (const float*)d_in[10];
    float* out = (float*)d_out;

    const int* src = eidx;
    const int* dst = eidx + N_EDGES;

    auto align = [](size_t v) { return (v + 255) & ~(size_t)255; };
    char* w = (char*)d_ws;
    int* deg  = (int*)w;  w += align(sizeof(int) * DEG_CAP);
    int* esrc = (int*)w;  w += align(sizeof(int) * (size_t)N_NODES * ROW_CAP);
    unsigned short* H1b = (unsigned short*)w;  w += align(2ull * PAD_NODES * 128);
    unsigned short* H2b = (unsigned short*)w;  w += align(2ull * PAD_NODES * 128);
    unsigned short* Wt0 = (unsigned short*)w;  w += align(2ull * 256 * 128);
    unsigned short* Wt1 = (unsigned short*)w;  w += align(2ull * 256 * 128);
    unsigned short* Wt2 = (unsigned short*)w;  w += align(2ull * 128 * 128);
    unsigned short* T   = (unsigned short*)w;  w += align(2ull * PAD_NODES * 128);
    unsigned short* Sb  = (unsigned short*)w;  w += align(2ull * PAD_NODES * 128);
    (void)ws_size; (void)n_in; (void)in_sizes; (void)out_size;

    // ---- prep: deg zero + W casts
    prep_kernel<<<(DEG_CAP / 4 + 81920 + 255) / 256, 256, 0, stream>>>(
        Wr0, Ws0, Wr1, Ws1, Wr2, Ws2, Wt0, Wt1, Wt2, deg);

    // ---- layer 1: mm (fp32 X) with place PROLOGUE fused (R16)
    mm_kernel<128, true, true><<<dim3(PAD_NODES / 128, 2), 256, 0, stream>>>(
        x, Wt0, T, Sb, src, dst, deg, esrc);
    aggregate_kernel<128, false><<<N_NODES / 16, 256, 0, stream>>>(T, Sb, br0, deg, esrc, H1b, nullptr);

    // ---- layer 2
    mm_kernel<128, false, false><<<dim3(PAD_NODES / 128, 2), 256, 0, stream>>>(
        H1b, Wt1, T, Sb, nullptr, nullptr, nullptr, nullptr);
    aggregate_kernel<128, false><<<N_NODES / 16, 256, 0, stream>>>(T, Sb, br1, deg, esrc, H2b, nullptr);

    // ---- layer 3 (fused log_softmax, fp32 out)
    mm_kernel<64, false, false><<<dim3(PAD_NODES / 128, 1), 256, 0, stream>>>(
        H2b, Wt2, T, Sb, nullptr, nullptr, nullptr, nullptr);
    aggregate_kernel<64, true><<<N_NODES / 32, 256, 0, stream>>>(T, Sb, br2, deg, esrc, nullptr, out);
}

// Round 7
// 212.535 us; speedup vs baseline: 1.0311x; 1.0311x over previous
//
#include <hip/hip_runtime.h>
#include <hip/hip_bf16.h>

// GraphConv x3 + ReLU + log_softmax on MI355X — bf16/MFMA pipeline.
// Per layer: [T|S] = H @ [Wr|Ws] via mfma_f32_16x16x32_bf16, then atomic-free
// aggregation (gather, fp32 accum): H' = relu(sum_j T[esrc[j]] + br + S).
// Layer 3 fuses log_softmax (8-lane shuffle groups), fp32 out.
// LEDGER:
// R11/R16 (FAILED +6/+13): place fused into mm1 (trailing / prologue) — the
//      place phase costs ~40us REGARDLESS of fusion/occupancy arrangement.
//      R12 (NEUTRAL): deg line-spread. place is off-limits now (3 failures).
// R13/R14 (NEUTRAL/REGR): per-XCD L2 residency for the T gather is
//      structurally impossible (working set > 4MB at >=1 line/edge);
//      NT sub-line stores bypass write-combining (R14 regression).
// R15 (WIN 212->205.8): mm epilogue via swizzled-LDS transpose -> 16B
//      coalesced stores. Partial-line global writes cost ~2x nominal.
// R17: fp8-e4m3 T for layers 1-2. Agg gather row: 256B (2 lines) -> 128B
//      (1 line) per edge — line count halves => agg time ~halves whether
//      L3-BW-bound or MSHR*latency-bound. S/bias/H/layer-3 stay bf16/fp32
//      (only the summed term is quantized). Pack: manual bf16->e4m3 RNE
//      (FTZ < 2^-6) in mm epilogue; unpack: v_cvt_f32_fp8 (OCP on gfx950)
//      with bit-exact manual fallback.

#define N_NODES 40000
#define N_EDGES 640000
#define PAD_NODES 40064        // 313 * 128
#define DEG_CAP   40960        // int4-aligned >= N_NODES
#define ROW_CAP   64           // esrc slots per node

typedef float v4f __attribute__((ext_vector_type(4)));
typedef float v2f __attribute__((ext_vector_type(2)));
typedef short short8 __attribute__((ext_vector_type(8)));

__device__ inline unsigned short f2b(float f) {  // RNE fp32->bf16
    unsigned u = __float_as_uint(f);
    return (unsigned short)((u + 0x7fffu + ((u >> 16) & 1u)) >> 16);
}

// bf16 -> fp8 e4m3 (OCP), RNE, FTZ below 2^-6, clamp to 448.
__device__ inline unsigned b2f8(unsigned short us) {
    unsigned s  = ((unsigned)us >> 8) & 0x80u;
    unsigned mag = us & 0x7fffu;
    unsigned e8 = mag >> 7, m7 = mag & 0x7fu;
    unsigned out;
    if (e8 < 121u) out = 0u;                 // FTZ (< 2^-6)
    else if (e8 > 135u) out = 0x7eu;         // clamp 448
    else {
        unsigned e4 = e8 - 120u;             // 1..15
        unsigned r  = (m7 + 7u + ((m7 >> 4) & 1u)) >> 4;  // RNE 7->3 bits
        if (r == 8u) { r = 0u; e4++; }
        out = (e4 > 15u || (e4 == 15u && r > 6u)) ? 0x7eu : ((e4 << 3) | r);
    }
    return s | out;
}

// fp8 e4m3 -> f32. HW cvt when available; manual fallback is bit-exact on
// our data (no denorms stored — FTZ pack; no NaN).
#if __has_builtin(__builtin_amdgcn_cvt_f32_fp8)
#define F8TOF(w, sel) __builtin_amdgcn_cvt_f32_fp8((int)(w), (sel))
#else
__device__ inline float f8tof_(unsigned b) {
    unsigned e = (b >> 3) & 15u;
    unsigned bits = ((b & 0x80u) << 24) |
                    (e ? (((e + 120u) << 23) | ((b & 7u) << 20)) : 0u);
    return __uint_as_float(bits);
}
#define F8TOF(w, sel) f8tof_(((unsigned)(w) >> ((sel) * 8)) & 0xffu)
#endif

// ---------------------------------------------------------------- prep
// deg zero + W transpose+cast to bf16.
__global__ __launch_bounds__(256) void prep_kernel(const float* __restrict__ Wr0, const float* __restrict__ Ws0,
                                                   const float* __restrict__ Wr1, const float* __restrict__ Ws1,
                                                   const float* __restrict__ Wr2, const float* __restrict__ Ws2,
                                                   unsigned short* __restrict__ Wt0,
                                                   unsigned short* __restrict__ Wt1,
                                                   unsigned short* __restrict__ Wt2,
                                                   int* __restrict__ deg) {
    int tid = blockIdx.x * 256 + threadIdx.x;
    if (tid < DEG_CAP / 4) {
        ((int4*)deg)[tid] = make_int4(0, 0, 0, 0);
    } else {
        int t = tid - DEG_CAP / 4;
        if (t < 32768) {
            int n = t >> 7, k = t & 127;
            const float* W = (n < 128) ? Wr0 : Ws0;
            Wt0[t] = f2b(W[k * 128 + (n & 127)]);
        } else if (t < 65536) {
            int u = t - 32768;
            int n = u >> 7, k = u & 127;
            const float* W = (n < 128) ? Wr1 : Ws1;
            Wt1[u] = f2b(W[k * 128 + (n & 127)]);
        } else if (t < 81920) {
            int u = t - 65536;
            int n = u >> 7, k = u & 127;
            const float* W = (n < 64) ? Wr2 : Ws2;
            Wt2[u] = f2b(W[k * 64 + (n & 63)]);
        }
    }
}

// ---------------------------------------------------------------- edge placement
// 1 edge/thread (max TLP): slot = atomicAdd(deg[dst]); esrc[dst*64+slot]=src.
__global__ __launch_bounds__(256) void place_kernel(const int* __restrict__ src,
                                                    const int* __restrict__ dst,
                                                    int* __restrict__ deg,
                                                    int* __restrict__ esrc) {
    int e = blockIdx.x * 256 + threadIdx.x;
    if (e < N_EDGES) {
        int d = dst[e];
        int r = atomicAdd(&deg[d], 1);
        if (r < ROW_CAP) esrc[(size_t)d * ROW_CAP + r] = src[e];
    }
}

// ---------------------------------------------------------------- MFMA matmul
// A: [PAD_NODES][128] (bf16, or fp32 when F32 — converted during staging).
// Wt: [2*DO][128] bf16 pre-transposed. Block 256 thr = 4 waves, tile 128x128.
// K staged in 2 halves of 64. 3 blocks/CU co-residency.
// Epilogue (R15): swizzled LDS transpose -> 16B coalesced stores; zeros at
// node == N_NODES (the aggregate's dummy/pad row).
// DO=128: n0==0 block writes T in FP8 (row 128B = 1 line, R17); n0==1
// writes S bf16. DO=64: both halves bf16 (layer 3 precision kept).
template <int DO, bool F32>
__global__ __launch_bounds__(256, 3) void mm_kernel(const void* __restrict__ Ain,
                                                    const unsigned short* __restrict__ Wt,
                                                    void* __restrict__ Tout,
                                                    unsigned short* __restrict__ S) {
    __shared__ unsigned short Smem[128 * 128];   // 32 KB: staging + epilogue
    unsigned short* As = Smem;                   // [128][64] K-half
    unsigned short* Bs = Smem + 128 * 64;        // [128][64]

    const int tid = threadIdx.x;
    const int m0  = blockIdx.x * 128;
    const int n0  = blockIdx.y * 128;

    const int wave = tid >> 6;
    const int lane = tid & 63;
    const int wr   = (wave >> 1) * 64;
    const int wc   = (wave & 1) * 64;
    const int qm   = lane & 15;
    const int k8   = (lane >> 4) * 8;

    v4f acc[4][4];
#pragma unroll
    for (int i = 0; i < 4; i++)
#pragma unroll
        for (int j = 0; j < 4; j++) acc[i][j] = (v4f)(0.0f);

#pragma unroll
    for (int half = 0; half < 2; half++) {
        // ---- stage A half: 128 rows x 64 k
        if (F32) {
            const float4* Xg = (const float4*)Ain;   // row pitch = 32 float4
#pragma unroll
            for (int i = 0; i < 8; i++) {
                int idx = i * 256 + tid;             // 0..2047 (float4 slots)
                int row = idx >> 4, c4 = idx & 15;   // 16 float4 per row-half
                int gr = m0 + row;
                if (gr > N_NODES - 1) gr = N_NODES - 1;  // pad tile: clamp
                float4 v = Xg[(size_t)gr * 32 + half * 16 + c4];
                uint2 p;
                p.x = (unsigned)f2b(v.x) | ((unsigned)f2b(v.y) << 16);
                p.y = (unsigned)f2b(v.z) | ((unsigned)f2b(v.w) << 16);
                ((uint2*)As)[idx] = p;
            }
        } else {
            const unsigned short* Ab = (const unsigned short*)Ain;
#pragma unroll
            for (int i = 0; i < 4; i++) {
                int idx = i * 256 + tid;             // 0..1023 (uint4 slots)
                int row = idx >> 3, c8 = idx & 7;    // 8 uint4 per row-half
                ((uint4*)As)[idx] =
                    *(const uint4*)(Ab + (size_t)(m0 + row) * 128 + half * 64 + c8 * 8);
            }
        }
        // ---- stage B half: Wt rows n0..n0+127, k-half
        {
#pragma unroll
            for (int i = 0; i < 4; i++) {
                int idx = i * 256 + tid;
                int row = idx >> 3, c8 = idx & 7;
                ((uint4*)Bs)[idx] =
                    *(const uint4*)(Wt + (size_t)(n0 + row) * 128 + half * 64 + c8 * 8);
            }
        }
        __syncthreads();

#pragma unroll
        for (int ks = 0; ks < 2; ks++) {
            short8 af[4], bf[4];
#pragma unroll
            for (int i = 0; i < 4; i++) {
                af[i] = *(const short8*)(const void*)(As + (wr + i * 16 + qm) * 64 + ks * 32 + k8);
                bf[i] = *(const short8*)(const void*)(Bs + (wc + i * 16 + qm) * 64 + ks * 32 + k8);
            }
#pragma unroll
            for (int mi = 0; mi < 4; mi++)
#pragma unroll
                for (int ni = 0; ni < 4; ni++)
                    acc[mi][ni] = __builtin_amdgcn_mfma_f32_16x16x32_bf16(af[mi], bf[ni], acc[mi][ni], 0, 0, 0);
        }
        __syncthreads();
    }

    // ---- R15 epilogue: swizzled LDS transpose (bf16 in Smem).
    // C/D layout: col=lane&15, row=(lane>>4)*4+reg  [m89-verified]
#pragma unroll
    for (int mi = 0; mi < 4; mi++) {
        const int rowBase = wr + mi * 16 + ((lane >> 4) << 2);
#pragma unroll
        for (int r = 0; r < 4; r++) {
            const int row = rowBase + r;
            const int sw  = ((row >> 2) & 3) << 4;
#pragma unroll
            for (int ni = 0; ni < 4; ni++) {
                const int c = wc + ni * 16 + qm;
                Smem[row * 128 + (c ^ sw)] = f2b(acc[mi][ni][r]);
            }
        }
    }
    __syncthreads();

    // node == N_NODES -> write ZEROS (dummy row read by aggregate pad slots).
    if (DO == 128 && n0 == 0) {
        // ---- fp8 T path (R17): 128 rows x 128 cols fp8 = 1024 x 16B chunks
        unsigned char* T8 = (unsigned char*)Tout;
#pragma unroll
        for (int i = 0; i < 4; i++) {
            const int chunk = i * 256 + tid;     // 0..1023
            const int row   = chunk >> 3;        // 8 chunks/row
            const int c0    = (chunk & 7) * 16;  // 16 dims per chunk
            const int sw    = ((row >> 2) & 3) << 4;
            const int node  = m0 + row;
            if (node <= N_NODES) {
                uint4 v = make_uint4(0, 0, 0, 0);
                if (node < N_NODES) {
                    const unsigned short* p = Smem + row * 128 + (c0 ^ sw);
                    unsigned wds[4];
#pragma unroll
                    for (int w4 = 0; w4 < 4; w4++) {
                        wds[w4] =  b2f8(p[w4 * 4 + 0])
                                | (b2f8(p[w4 * 4 + 1]) << 8)
                                | (b2f8(p[w4 * 4 + 2]) << 16)
                                | (b2f8(p[w4 * 4 + 3]) << 24);
                    }
                    v = make_uint4(wds[0], wds[1], wds[2], wds[3]);
                }
                *(uint4*)(T8 + (size_t)node * 128 + c0) = v;
            }
        }
    } else {
        // ---- bf16 path: 128 rows x 128 cols bf16 = 2048 x 16B chunks
        unsigned short* T = (unsigned short*)Tout;
#pragma unroll
        for (int i = 0; i < 8; i++) {
            const int chunk = i * 256 + tid;
            const int row   = chunk >> 4;
            const int c0    = (chunk & 15) * 8;  // 8 ushorts = 16 B
            const int sw    = ((row >> 2) & 3) << 4;
            const int node  = m0 + row;
            if (node <= N_NODES) {
                uint4 v = make_uint4(0, 0, 0, 0);
                if (node < N_NODES)
                    v = *(const uint4*)(Smem + row * 128 + (c0 ^ sw));
                if (DO == 128) {
                    *(uint4*)(S + (size_t)node * 128 + c0) = v;   // n0==1: S
                } else {
                    if (c0 < 64) *(uint4*)(T + (size_t)node * 64 + c0) = v;
                    else         *(uint4*)(S + (size_t)node * 64 + (c0 - 64)) = v;
                }
            }
        }
    }
}

// ---------------------------------------------------------------- aggregate
// H[n] = relu(sum_j T[esrc[n*64+j]] + br + S[n]); fp32 accum.
// TPN = DO/8 threads/node, 8 dims each. 8-wide unrolled; pad slots masked
// in-register to dummy node 40000 (zero row). v2f acc for v_pk_add_f32.
// FP8T (layers 1-2): T row = 128 fp8 = 1 line; uint2 (8B) gather + v_cvt.
__device__ inline void addp(v2f* a, uint4 q) {
    v2f t0 = { __uint_as_float(q.x << 16), __uint_as_float(q.x & 0xffff0000u) };
    v2f t1 = { __uint_as_float(q.y << 16), __uint_as_float(q.y & 0xffff0000u) };
    v2f t2 = { __uint_as_float(q.z << 16), __uint_as_float(q.z & 0xffff0000u) };
    v2f t3 = { __uint_as_float(q.w << 16), __uint_as_float(q.w & 0xffff0000u) };
    a[0] += t0; a[1] += t1; a[2] += t2; a[3] += t3;
}
__device__ inline void addp8(v2f* a, uint2 q) {
    v2f t0 = { F8TOF(q.x, 0), F8TOF(q.x, 1) };
    v2f t1 = { F8TOF(q.x, 2), F8TOF(q.x, 3) };
    v2f t2 = { F8TOF(q.y, 0), F8TOF(q.y, 1) };
    v2f t3 = { F8TOF(q.y, 2), F8TOF(q.y, 3) };
    a[0] += t0; a[1] += t1; a[2] += t2; a[3] += t3;
}

template <int DO, bool LAST, bool FP8T>
__global__ __launch_bounds__(256) void aggregate_kernel(const void* __restrict__ Tin,
                                                        const unsigned short* __restrict__ S,
                                                        const float* __restrict__ br,
                                                        const int* __restrict__ deg,
                                                        const int* __restrict__ esrc,
                                                        unsigned short* __restrict__ Hout,
                                                        float* __restrict__ Fout) {
    constexpr int TPN = DO / 8;        // 16 (DO=128) or 8 (DO=64)
    constexpr int G   = 256 / TPN;     // nodes per block
    const int lane = threadIdx.x % TPN;
    const int n    = blockIdx.x * G + threadIdx.x / TPN;

    int cnt = deg[n];
    if (cnt > ROW_CAP) cnt = ROW_CAP;  // safety (never expected)
    const int* erow = esrc + (size_t)n * ROW_CAP;
    const uint4* T4 = (const uint4*)Tin;
    const uint2* T2 = (const uint2*)Tin;

    const uint4  sv = ((const uint4*)S)[(size_t)n * TPN + lane];
    const float4 b0 = ((const float4*)br)[lane * 2];
    const float4 b1 = ((const float4*)br)[lane * 2 + 1];

    v2f acc[4];
    acc[0] = (v2f)(0.0f); acc[1] = (v2f)(0.0f);
    acc[2] = (v2f)(0.0f); acc[3] = (v2f)(0.0f);

    for (int o = 0; o < cnt; o += 8) {
        int4 i0 = *(const int4*)(erow + o);
        int4 i1 = *(const int4*)(erow + o + 4);
        // mask pad slots (uninitialized) -> dummy zero row (safe addressing)
        i0.x = (o + 0 < cnt) ? i0.x : N_NODES;
        i0.y = (o + 1 < cnt) ? i0.y : N_NODES;
        i0.z = (o + 2 < cnt) ? i0.z : N_NODES;
        i0.w = (o + 3 < cnt) ? i0.w : N_NODES;
        i1.x = (o + 4 < cnt) ? i1.x : N_NODES;
        i1.y = (o + 5 < cnt) ? i1.y : N_NODES;
        i1.z = (o + 6 < cnt) ? i1.z : N_NODES;
        i1.w = (o + 7 < cnt) ? i1.w : N_NODES;
        if (FP8T) {
            uint2 q0 = T2[(size_t)i0.x * TPN + lane];
            uint2 q1 = T2[(size_t)i0.y * TPN + lane];
            uint2 q2 = T2[(size_t)i0.z * TPN + lane];
            uint2 q3 = T2[(size_t)i0.w * TPN + lane];
            uint2 q4 = T2[(size_t)i1.x * TPN + lane];
            uint2 q5 = T2[(size_t)i1.y * TPN + lane];
            uint2 q6 = T2[(size_t)i1.z * TPN + lane];
            uint2 q7 = T2[(size_t)i1.w * TPN + lane];
            addp8(acc, q0); addp8(acc, q1); addp8(acc, q2); addp8(acc, q3);
            addp8(acc, q4); addp8(acc, q5); addp8(acc, q6); addp8(acc, q7);
        } else {
            uint4 q0 = T4[(size_t)i0.x * TPN + lane];
            uint4 q1 = T4[(size_t)i0.y * TPN + lane];
            uint4 q2 = T4[(size_t)i0.z * TPN + lane];
            uint4 q3 = T4[(size_t)i0.w * TPN + lane];
            uint4 q4 = T4[(size_t)i1.x * TPN + lane];
            uint4 q5 = T4[(size_t)i1.y * TPN + lane];
            uint4 q6 = T4[(size_t)i1.z * TPN + lane];
            uint4 q7 = T4[(size_t)i1.w * TPN + lane];
            addp(acc, q0); addp(acc, q1); addp(acc, q2); addp(acc, q3);
            addp(acc, q4); addp(acc, q5); addp(acc, q6); addp(acc, q7);
        }
    }
    addp(acc, sv);  // root term (bf16, exact path)

    float v[8];
    v[0] = fmaxf(acc[0].x + b0.x, 0.f); v[1] = fmaxf(acc[0].y + b0.y, 0.f);
    v[2] = fmaxf(acc[1].x + b0.z, 0.f); v[3] = fmaxf(acc[1].y + b0.w, 0.f);
    v[4] = fmaxf(acc[2].x + b1.x, 0.f); v[5] = fmaxf(acc[2].y + b1.y, 0.f);
    v[6] = fmaxf(acc[3].x + b1.z, 0.f); v[7] = fmaxf(acc[3].y + b1.w, 0.f);

    if (LAST) {
        // DO=64, TPN=8: 8-lane shuffle groups; log_softmax
        float m = v[0];
#pragma unroll
        for (int i = 1; i < 8; i++) m = fmaxf(m, v[i]);
#pragma unroll
        for (int off = 4; off; off >>= 1) m = fmaxf(m, __shfl_xor(m, off, 64));
        float es = 0.f;
#pragma unroll
        for (int i = 0; i < 8; i++) es += expf(v[i] - m);
#pragma unroll
        for (int off = 4; off; off >>= 1) es += __shfl_xor(es, off, 64);
        float lse = m + logf(es);
        float4 o0 = make_float4(v[0] - lse, v[1] - lse, v[2] - lse, v[3] - lse);
        float4 o1 = make_float4(v[4] - lse, v[5] - lse, v[6] - lse, v[7] - lse);
        ((float4*)Fout)[(size_t)n * 16 + lane * 2]     = o0;
        ((float4*)Fout)[(size_t)n * 16 + lane * 2 + 1] = o1;
    } else {
        uint4 o;
        o.x = (unsigned)f2b(v[0]) | ((unsigned)f2b(v[1]) << 16);
        o.y = (unsigned)f2b(v[2]) | ((unsigned)f2b(v[3]) << 16);
        o.z = (unsigned)f2b(v[4]) | ((unsigned)f2b(v[5]) << 16);
        o.w = (unsigned)f2b(v[6]) | ((unsigned)f2b(v[7]) << 16);
        ((uint4*)Hout)[(size_t)n * TPN + lane] = o;
    }
}

// ---------------------------------------------------------------- launch

extern "C" void kernel_launch(void* const* d_in, const int* in_sizes, int n_in,
                              void* d_out, int out_size, void* d_ws, size_t ws_size,
                              hipStream_t stream) {
    const float* x    = (const float*)d_in[0];
    const int*   eidx = (const int*)d_in[1];   // [2, E] int32
    const float* Wr0  = (const float*)d_in[2];
    const float* br0  = (const float*)d_in[3];
    const float* Ws0  = (const float*)d_in[4];
    const float* Wr1  = (const float*)d_in[5];
    const float* br1  = (const float*)d_in[6];
    const float* Ws1  = (const float*)d_in[7];
    const float* Wr2  = (const float*)d_in[8];
    const float* br2  = (const float*)d_in[9];
    const float* Ws2  = (const float*)d_in[10];
    float* out = (float*)d_out;

    const int* src = eidx;
    const int* dst = eidx + N_EDGES;

    auto align = [](size_t v) { return (v + 255) & ~(size_t)255; };
    char* w = (char*)d_ws;
    int* deg  = (int*)w;  w += align(sizeof(int) * DEG_CAP);
    int* esrc = (int*)w;  w += align(sizeof(int) * (size_t)N_NODES * ROW_CAP);
    unsigned short* H1b = (unsigned short*)w;  w += align(2ull * PAD_NODES * 128);
    unsigned short* H2b = (unsigned short*)w;  w += align(2ull * PAD_NODES * 128);
    unsigned short* Wt0 = (unsigned short*)w;  w += align(2ull * 256 * 128);
    unsigned short* Wt1 = (unsigned short*)w;  w += align(2ull * 256 * 128);
    unsigned short* Wt2 = (unsigned short*)w;  w += align(2ull * 128 * 128);
    void*           T   = (void*)w;            w += align(2ull * PAD_NODES * 128);
    unsigned short* Sb  = (unsigned short*)w;  w += align(2ull * PAD_NODES * 128);
    (void)ws_size; (void)n_in; (void)in_sizes; (void)out_size;

    // ---- prep: deg zero + W casts
    prep_kernel<<<(DEG_CAP / 4 + 81920 + 255) / 256, 256, 0, stream>>>(
        Wr0, Ws0, Wr1, Ws1, Wr2, Ws2, Wt0, Wt1, Wt2, deg);

    // ---- edge placement (1 edge/thread, max TLP)
    place_kernel<<<(N_EDGES + 255) / 256, 256, 0, stream>>>(src, dst, deg, esrc);

    // ---- layer 1 (fp32 X read directly); T in fp8
    mm_kernel<128, true><<<dim3(PAD_NODES / 128, 2), 256, 0, stream>>>(x, Wt0, T, Sb);
    aggregate_kernel<128, false, true><<<N_NODES / 16, 256, 0, stream>>>(T, Sb, br0, deg, esrc, H1b, nullptr);

    // ---- layer 2; T in fp8
    mm_kernel<128, false><<<dim3(PAD_NODES / 128, 2), 256, 0, stream>>>(H1b, Wt1, T, Sb);
    aggregate_kernel<128, false, true><<<N_NODES / 16, 256, 0, stream>>>(T, Sb, br1, deg, esrc, H2b, nullptr);

    // ---- layer 3 (bf16 T, fused log_softmax, fp32 out)
    mm_kernel<64, false><<<dim3(PAD_NODES / 128, 1), 256, 0, stream>>>(H2b, Wt2, T, Sb);
    aggregate_kernel<64, true, false><<<N_NODES / 32, 256, 0, stream>>>(T, Sb, br2, deg, esrc, nullptr, out);
}

// Round 8
// 203.282 us; speedup vs baseline: 1.0781x; 1.0455x over previous
//
#include <hip/hip_runtime.h>
#include <hip/hip_bf16.h>

// GraphConv x3 + ReLU + log_softmax on MI355X — bf16/MFMA pipeline.
// Per layer: [T|S] = H @ [Wr|Ws] via mfma_f32_16x16x32_bf16, then atomic-free
// aggregation (gather, fp32 accum): H' = relu(sum_j T[esrc[j]] + br + S).
// Layer 3 fuses log_softmax (8-lane shuffle groups), fp32 out.
// LEDGER:
// R11/R16 (FAILED): place fusions — MISATTRIBUTED. R17 PMC showed place is
//      only ~10us; mm1 (fp32-staging) was the hidden ~50us pole.
// R13/R14: L2-residency for the gather impossible; NT sub-line stores bad.
// R15 (WIN 212->205.8): mm epilogue swizzled-LDS transpose -> 16B stores.
//      Partial-line global writes cost ~2x nominal.
// R17 (FAILED perf, key insight): fp8 T with SAME load count (16x uint2)
//      gave NO agg gain -> agg is VMEM-op-COUNT x latency bound, not
//      byte-bound. Also mm1 = 52us standalone (FETCH 21.3MB fp32 x).
// R18: (a) x pre-cast to bf16 in prep (mm1 becomes mm2: half fetch, no
//      f2b staging); (b) mm launch_bounds (256,4) — 128KB LDS/CU, +33%
//      TLP for latency-bound staging; (c) fp8 T agg restructured to
//      TPN=8 + ONE uint4 load/edge (8 loads vs bf16's 16 — the actual
//      count halving); pack in-register via v_cvt_pk_fp8_f32.

#define N_NODES 40000
#define N_EDGES 640000
#define PAD_NODES 40064        // 313 * 128
#define DEG_CAP   40960        // int4-aligned >= N_NODES
#define ROW_CAP   64           // esrc slots per node

typedef float v4f __attribute__((ext_vector_type(4)));
typedef float v2f __attribute__((ext_vector_type(2)));
typedef short short8 __attribute__((ext_vector_type(8)));

__device__ inline unsigned short f2b(float f) {  // RNE fp32->bf16
    unsigned u = __float_as_uint(f);
    return (unsigned short)((u + 0x7fffu + ((u >> 16) & 1u)) >> 16);
}

// bf16 -> fp8 e4m3 (OCP), RNE, FTZ below 2^-6, clamp to 448 (fallback path).
__device__ inline unsigned b2f8(unsigned short us) {
    unsigned s  = ((unsigned)us >> 8) & 0x80u;
    unsigned mag = us & 0x7fffu;
    unsigned e8 = mag >> 7, m7 = mag & 0x7fu;
    unsigned out;
    if (e8 < 121u) out = 0u;                 // FTZ (< 2^-6)
    else if (e8 > 135u) out = 0x7eu;         // clamp 448
    else {
        unsigned e4 = e8 - 120u;             // 1..15
        unsigned r  = (m7 + 7u + ((m7 >> 4) & 1u)) >> 4;  // RNE 7->3 bits
        if (r == 8u) { r = 0u; e4++; }
        out = (e4 > 15u || (e4 == 15u && r > 6u)) ? 0x7eu : ((e4 << 3) | r);
    }
    return s | out;
}

// 4x f32 -> 4x fp8 packed in one dword. HW pk-cvt when available.
__device__ inline unsigned pack4_fp8(float f0, float f1, float f2, float f3) {
#if __has_builtin(__builtin_amdgcn_cvt_pk_fp8_f32)
    int w = __builtin_amdgcn_cvt_pk_fp8_f32(f0, f1, 0, false);
    w = __builtin_amdgcn_cvt_pk_fp8_f32(f2, f3, w, true);
    return (unsigned)w;
#else
    return b2f8(f2b(f0)) | (b2f8(f2b(f1)) << 8) |
           (b2f8(f2b(f2)) << 16) | (b2f8(f2b(f3)) << 24);
#endif
}

// fp8 e4m3 -> f32. HW cvt when available; manual fallback (denorms->0).
#if __has_builtin(__builtin_amdgcn_cvt_f32_fp8)
#define F8TOF(w, sel) __builtin_amdgcn_cvt_f32_fp8((int)(w), (sel))
#else
__device__ inline float f8tof_(unsigned b) {
    unsigned e = (b >> 3) & 15u;
    unsigned bits = ((b & 0x80u) << 24) |
                    (e ? (((e + 120u) << 23) | ((b & 7u) << 20)) : 0u);
    return __uint_as_float(bits);
}
#define F8TOF(w, sel) f8tof_(((unsigned)(w) >> ((sel) * 8)) & 0xffu)
#endif

// ---------------------------------------------------------------- prep
// deg zero + W transpose+cast + x -> bf16 pre-cast (R18a).
__global__ __launch_bounds__(256) void prep_kernel(const float* __restrict__ Wr0, const float* __restrict__ Ws0,
                                                   const float* __restrict__ Wr1, const float* __restrict__ Ws1,
                                                   const float* __restrict__ Wr2, const float* __restrict__ Ws2,
                                                   const float* __restrict__ x,
                                                   unsigned short* __restrict__ Wt0,
                                                   unsigned short* __restrict__ Wt1,
                                                   unsigned short* __restrict__ Wt2,
                                                   unsigned short* __restrict__ Xb,
                                                   int* __restrict__ deg) {
    int tid = blockIdx.x * 256 + threadIdx.x;
    if (tid < DEG_CAP / 4) {
        ((int4*)deg)[tid] = make_int4(0, 0, 0, 0);
        return;
    }
    int t = tid - DEG_CAP / 4;
    if (t < 32768) {
        int n = t >> 7, k = t & 127;
        const float* W = (n < 128) ? Wr0 : Ws0;
        Wt0[t] = f2b(W[k * 128 + (n & 127)]);
    } else if (t < 65536) {
        int u = t - 32768;
        int n = u >> 7, k = u & 127;
        const float* W = (n < 128) ? Wr1 : Ws1;
        Wt1[u] = f2b(W[k * 128 + (n & 127)]);
    } else if (t < 81920) {
        int u = t - 65536;
        int n = u >> 7, k = u & 127;
        const float* W = (n < 64) ? Wr2 : Ws2;
        Wt2[u] = f2b(W[k * 64 + (n & 63)]);
    } else {
        int u = t - 81920;                    // 0..639999: 8 floats each
        if (u < (N_NODES * 128) / 8) {
            float4 a = ((const float4*)x)[u * 2];
            float4 b = ((const float4*)x)[u * 2 + 1];
            uint4 o;
            o.x = (unsigned)f2b(a.x) | ((unsigned)f2b(a.y) << 16);
            o.y = (unsigned)f2b(a.z) | ((unsigned)f2b(a.w) << 16);
            o.z = (unsigned)f2b(b.x) | ((unsigned)f2b(b.y) << 16);
            o.w = (unsigned)f2b(b.z) | ((unsigned)f2b(b.w) << 16);
            ((uint4*)Xb)[u] = o;
        }
    }
}

// ---------------------------------------------------------------- edge placement
// 1 edge/thread (max TLP): slot = atomicAdd(deg[dst]); esrc[dst*64+slot]=src.
// (~10us per R17 subtraction — leave alone.)
__global__ __launch_bounds__(256) void place_kernel(const int* __restrict__ src,
                                                    const int* __restrict__ dst,
                                                    int* __restrict__ deg,
                                                    int* __restrict__ esrc) {
    int e = blockIdx.x * 256 + threadIdx.x;
    if (e < N_EDGES) {
        int d = dst[e];
        int r = atomicAdd(&deg[d], 1);
        if (r < ROW_CAP) esrc[(size_t)d * ROW_CAP + r] = src[e];
    }
}

// ---------------------------------------------------------------- MFMA matmul
// A: [PAD_NODES][128] bf16 (always — x pre-cast in prep). Wt: [2*DO][128]
// bf16 pre-transposed. Block 256 thr = 4 waves, tile 128x128; K in 2 halves
// of 64. launch_bounds (256,4): 4 blocks/CU (128KB LDS), +33% TLP (R18b).
// Epilogue (R15): swizzled LDS transpose -> coalesced stores; zeros at
// node == N_NODES (dummy row). DO=128: n0==0 writes T in FP8 (in-register
// pk-cvt, 16B stores); n0==1 writes S bf16. DO=64: both halves bf16.
template <int DO>
__global__ __launch_bounds__(256, 4) void mm_kernel(const unsigned short* __restrict__ Ab,
                                                    const unsigned short* __restrict__ Wt,
                                                    void* __restrict__ Tout,
                                                    unsigned short* __restrict__ S) {
    __shared__ unsigned short Smem[128 * 128];   // 32 KB: staging + epilogue
    unsigned short* As = Smem;                   // [128][64] K-half
    unsigned short* Bs = Smem + 128 * 64;        // [128][64]

    const int tid = threadIdx.x;
    const int m0  = blockIdx.x * 128;
    const int n0  = blockIdx.y * 128;

    const int wave = tid >> 6;
    const int lane = tid & 63;
    const int wr   = (wave >> 1) * 64;
    const int wc   = (wave & 1) * 64;
    const int qm   = lane & 15;
    const int k8   = (lane >> 4) * 8;

    v4f acc[4][4];
#pragma unroll
    for (int i = 0; i < 4; i++)
#pragma unroll
        for (int j = 0; j < 4; j++) acc[i][j] = (v4f)(0.0f);

#pragma unroll
    for (int half = 0; half < 2; half++) {
        // ---- stage A half: 128 rows x 64 k (bf16, 16B loads)
#pragma unroll
        for (int i = 0; i < 4; i++) {
            int idx = i * 256 + tid;             // 0..1023 (uint4 slots)
            int row = idx >> 3, c8 = idx & 7;    // 8 uint4 per row-half
            ((uint4*)As)[idx] =
                *(const uint4*)(Ab + (size_t)(m0 + row) * 128 + half * 64 + c8 * 8);
        }
        // ---- stage B half: Wt rows n0..n0+127, k-half
#pragma unroll
        for (int i = 0; i < 4; i++) {
            int idx = i * 256 + tid;
            int row = idx >> 3, c8 = idx & 7;
            ((uint4*)Bs)[idx] =
                *(const uint4*)(Wt + (size_t)(n0 + row) * 128 + half * 64 + c8 * 8);
        }
        __syncthreads();

#pragma unroll
        for (int ks = 0; ks < 2; ks++) {
            short8 af[4], bf[4];
#pragma unroll
            for (int i = 0; i < 4; i++) {
                af[i] = *(const short8*)(const void*)(As + (wr + i * 16 + qm) * 64 + ks * 32 + k8);
                bf[i] = *(const short8*)(const void*)(Bs + (wc + i * 16 + qm) * 64 + ks * 32 + k8);
            }
#pragma unroll
            for (int mi = 0; mi < 4; mi++)
#pragma unroll
                for (int ni = 0; ni < 4; ni++)
                    acc[mi][ni] = __builtin_amdgcn_mfma_f32_16x16x32_bf16(af[mi], bf[ni], acc[mi][ni], 0, 0, 0);
        }
        __syncthreads();
    }

    // ---- R15 epilogue: swizzled LDS transpose (bf16 in Smem).
    // C/D layout: col=lane&15, row=(lane>>4)*4+reg  [m89-verified]
#pragma unroll
    for (int mi = 0; mi < 4; mi++) {
        const int rowBase = wr + mi * 16 + ((lane >> 4) << 2);
#pragma unroll
        for (int r = 0; r < 4; r++) {
            const int row = rowBase + r;
            const int sw  = ((row >> 2) & 3) << 4;
#pragma unroll
            for (int ni = 0; ni < 4; ni++) {
                const int c = wc + ni * 16 + qm;
                Smem[row * 128 + (c ^ sw)] = f2b(acc[mi][ni][r]);
            }
        }
    }
    __syncthreads();

    // node == N_NODES -> write ZEROS (dummy row read by aggregate pad slots).
    if (DO == 128 && n0 == 0) {
        // ---- fp8 T: 1024 chunks of 16 dims; 2 LDS b128 reads + 8 pk-cvt +
        // one 16B store per chunk (in-register pack — no scalar LDS reads).
        unsigned char* T8 = (unsigned char*)Tout;
#pragma unroll
        for (int i = 0; i < 4; i++) {
            const int chunk = i * 256 + tid;     // 0..1023
            const int row   = chunk >> 3;        // 8 chunks/row
            const int c0    = (chunk & 7) * 16;  // 16 dims per chunk
            const int sw    = ((row >> 2) & 3) << 4;
            const int node  = m0 + row;
            if (node <= N_NODES) {
                uint4 v = make_uint4(0, 0, 0, 0);
                if (node < N_NODES) {
                    const unsigned short* p = Smem + row * 128 + (c0 ^ sw);
                    uint4 ha = *(const uint4*)p;        // dims c0..c0+7
                    uint4 hb = *(const uint4*)(p + 8);  // dims c0+8..c0+15
#define LOF(d) __uint_as_float((d) << 16)
#define HIF(d) __uint_as_float((d) & 0xffff0000u)
                    v.x = pack4_fp8(LOF(ha.x), HIF(ha.x), LOF(ha.y), HIF(ha.y));
                    v.y = pack4_fp8(LOF(ha.z), HIF(ha.z), LOF(ha.w), HIF(ha.w));
                    v.z = pack4_fp8(LOF(hb.x), HIF(hb.x), LOF(hb.y), HIF(hb.y));
                    v.w = pack4_fp8(LOF(hb.z), HIF(hb.z), LOF(hb.w), HIF(hb.w));
#undef LOF
#undef HIF
                }
                *(uint4*)(T8 + (size_t)node * 128 + c0) = v;
            }
        }
    } else {
        // ---- bf16 path: 2048 x 16B chunks
        unsigned short* T = (unsigned short*)Tout;
#pragma unroll
        for (int i = 0; i < 8; i++) {
            const int chunk = i * 256 + tid;
            const int row   = chunk >> 4;
            const int c0    = (chunk & 15) * 8;  // 8 ushorts = 16 B
            const int sw    = ((row >> 2) & 3) << 4;
            const int node  = m0 + row;
            if (node <= N_NODES) {
                uint4 v = make_uint4(0, 0, 0, 0);
                if (node < N_NODES)
                    v = *(const uint4*)(Smem + row * 128 + (c0 ^ sw));
                if (DO == 128) {
                    *(uint4*)(S + (size_t)node * 128 + c0) = v;   // n0==1: S
                } else {
                    if (c0 < 64) *(uint4*)(T + (size_t)node * 64 + c0) = v;
                    else         *(uint4*)(S + (size_t)node * 64 + (c0 - 64)) = v;
                }
            }
        }
    }
}

// ---------------------------------------------------------------- aggregate
// H[n] = relu(sum_j T[esrc[n*64+j]] + br + S[n]); fp32 accum.
// FP8T (layers 1-2, DO=128): TPN=8 lanes/node, 16 dims/lane, ONE uint4
// (16 fp8) gather per edge — 8 VMEM ops/edge vs bf16's 16 (R18c).
// Else (layer 3): TPN=8, 8 dims, uint4 bf16 gather. Pad slots masked
// in-register to dummy node 40000 (zero row).
__device__ inline void addp(v2f* a, uint4 q) {
    v2f t0 = { __uint_as_float(q.x << 16), __uint_as_float(q.x & 0xffff0000u) };
    v2f t1 = { __uint_as_float(q.y << 16), __uint_as_float(q.y & 0xffff0000u) };
    v2f t2 = { __uint_as_float(q.z << 16), __uint_as_float(q.z & 0xffff0000u) };
    v2f t3 = { __uint_as_float(q.w << 16), __uint_as_float(q.w & 0xffff0000u) };
    a[0] += t0; a[1] += t1; a[2] += t2; a[3] += t3;
}
__device__ inline void addp8w(v2f* a, unsigned w) {   // 4 fp8 -> 2 v2f
    v2f t0 = { F8TOF(w, 0), F8TOF(w, 1) };
    v2f t1 = { F8TOF(w, 2), F8TOF(w, 3) };
    a[0] += t0; a[1] += t1;
}
__device__ inline void addp16(v2f* a, uint4 q) {      // 16 fp8
    addp8w(a + 0, q.x); addp8w(a + 2, q.y);
    addp8w(a + 4, q.z); addp8w(a + 6, q.w);
}

template <int DO, bool LAST, bool FP8T>
__global__ __launch_bounds__(256) void aggregate_kernel(const void* __restrict__ Tin,
                                                        const unsigned short* __restrict__ S,
                                                        const float* __restrict__ br,
                                                        const int* __restrict__ deg,
                                                        const int* __restrict__ esrc,
                                                        unsigned short* __restrict__ Hout,
                                                        float* __restrict__ Fout) {
    constexpr int TPN = 8;             // lanes per node (both paths)
    constexpr int DPL = DO / TPN;      // dims per lane: 16 (fp8) or 8
    constexpr int G   = 256 / TPN;     // 32 nodes per block
    const int lane = threadIdx.x % TPN;
    const int n    = blockIdx.x * G + threadIdx.x / TPN;

    int cnt = deg[n];
    if (cnt > ROW_CAP) cnt = ROW_CAP;  // safety (never expected)
    const int* erow = esrc + (size_t)n * ROW_CAP;
    const uint4* T4 = (const uint4*)Tin;

    v2f acc[DPL / 2];
#pragma unroll
    for (int i = 0; i < DPL / 2; i++) acc[i] = (v2f)(0.0f);

    for (int o = 0; o < cnt; o += 8) {
        int4 i0 = *(const int4*)(erow + o);
        int4 i1 = *(const int4*)(erow + o + 4);
        // mask pad slots (uninitialized) -> dummy zero row (safe addressing)
        i0.x = (o + 0 < cnt) ? i0.x : N_NODES;
        i0.y = (o + 1 < cnt) ? i0.y : N_NODES;
        i0.z = (o + 2 < cnt) ? i0.z : N_NODES;
        i0.w = (o + 3 < cnt) ? i0.w : N_NODES;
        i1.x = (o + 4 < cnt) ? i1.x : N_NODES;
        i1.y = (o + 5 < cnt) ? i1.y : N_NODES;
        i1.z = (o + 6 < cnt) ? i1.z : N_NODES;
        i1.w = (o + 7 < cnt) ? i1.w : N_NODES;
        uint4 q0 = T4[(size_t)i0.x * TPN + lane];
        uint4 q1 = T4[(size_t)i0.y * TPN + lane];
        uint4 q2 = T4[(size_t)i0.z * TPN + lane];
        uint4 q3 = T4[(size_t)i0.w * TPN + lane];
        uint4 q4 = T4[(size_t)i1.x * TPN + lane];
        uint4 q5 = T4[(size_t)i1.y * TPN + lane];
        uint4 q6 = T4[(size_t)i1.z * TPN + lane];
        uint4 q7 = T4[(size_t)i1.w * TPN + lane];
        if (FP8T) {
            addp16(acc, q0); addp16(acc, q1); addp16(acc, q2); addp16(acc, q3);
            addp16(acc, q4); addp16(acc, q5); addp16(acc, q6); addp16(acc, q7);
        } else {
            addp(acc, q0); addp(acc, q1); addp(acc, q2); addp(acc, q3);
            addp(acc, q4); addp(acc, q5); addp(acc, q6); addp(acc, q7);
        }
    }

    // root term S (bf16, exact) + bias + relu
    float v[DPL];
#pragma unroll
    for (int h = 0; h < DPL / 8; h++) {
        uint4 sv = ((const uint4*)S)[(size_t)n * (DO / 8) + lane * (DPL / 8) + h];
        addp(acc + h * 4, sv);
    }
#pragma unroll
    for (int j = 0; j < DPL; j++) {
        float bj = br[lane * DPL + j];
        v[j] = fmaxf(((j & 1) ? acc[j >> 1].y : acc[j >> 1].x) + bj, 0.f);
    }

    if (LAST) {
        // DO=64, TPN=8: 8-lane shuffle groups; log_softmax
        float m = v[0];
#pragma unroll
        for (int i = 1; i < 8; i++) m = fmaxf(m, v[i]);
#pragma unroll
        for (int off = 4; off; off >>= 1) m = fmaxf(m, __shfl_xor(m, off, 64));
        float es = 0.f;
#pragma unroll
        for (int i = 0; i < 8; i++) es += expf(v[i] - m);
#pragma unroll
        for (int off = 4; off; off >>= 1) es += __shfl_xor(es, off, 64);
        float lse = m + logf(es);
        float4 o0 = make_float4(v[0] - lse, v[1] - lse, v[2] - lse, v[3] - lse);
        float4 o1 = make_float4(v[4] - lse, v[5] - lse, v[6] - lse, v[7] - lse);
        ((float4*)Fout)[(size_t)n * 16 + lane * 2]     = o0;
        ((float4*)Fout)[(size_t)n * 16 + lane * 2 + 1] = o1;
    } else {
#pragma unroll
        for (int h = 0; h < DPL / 8; h++) {
            uint4 o;
            o.x = (unsigned)f2b(v[h * 8 + 0]) | ((unsigned)f2b(v[h * 8 + 1]) << 16);
            o.y = (unsigned)f2b(v[h * 8 + 2]) | ((unsigned)f2b(v[h * 8 + 3]) << 16);
            o.z = (unsigned)f2b(v[h * 8 + 4]) | ((unsigned)f2b(v[h * 8 + 5]) << 16);
            o.w = (unsigned)f2b(v[h * 8 + 6]) | ((unsigned)f2b(v[h * 8 + 7]) << 16);
            ((uint4*)Hout)[(size_t)n * (DO / 8) + lane * (DPL / 8) + h] = o;
        }
    }
}

// ---------------------------------------------------------------- launch

extern "C" void kernel_launch(void* const* d_in, const int* in_sizes, int n_in,
                              void* d_out, int out_size, void* d_ws, size_t ws_size,
                              hipStream_t stream) {
    const float* x    = (const float*)d_in[0];
    const int*   eidx = (const int*)d_in[1];   // [2, E] int32
    const float* Wr0  = (const float*)d_in[2];
    const float* br0  = (const float*)d_in[3];
    const float* Ws0  = (const float*)d_in[4];
    const float* Wr1  = (const float*)d_in[5];
    const float* br1  = (const float*)d_in[6];
    const float* Ws1  = (const float*)d_in[7];
    const float* Wr2  = (const float*)d_in[8];
    const float* br2  = (const float*)d_in[9];
    const float* Ws2  = (const float*)d_in[10];
    float* out = (float*)d_out;

    const int* src = eidx;
    const int* dst = eidx + N_EDGES;

    auto align = [](size_t v) { return (v + 255) & ~(size_t)255; };
    char* w = (char*)d_ws;
    int* deg  = (int*)w;  w += align(sizeof(int) * DEG_CAP);
    int* esrc = (int*)w;  w += align(sizeof(int) * (size_t)N_NODES * ROW_CAP);
    unsigned short* Xb  = (unsigned short*)w;  w += align(2ull * PAD_NODES * 128);
    unsigned short* H1b = (unsigned short*)w;  w += align(2ull * PAD_NODES * 128);
    unsigned short* H2b = (unsigned short*)w;  w += align(2ull * PAD_NODES * 128);
    unsigned short* Wt0 = (unsigned short*)w;  w += align(2ull * 256 * 128);
    unsigned short* Wt1 = (unsigned short*)w;  w += align(2ull * 256 * 128);
    unsigned short* Wt2 = (unsigned short*)w;  w += align(2ull * 128 * 128);
    void*           T   = (void*)w;            w += align(2ull * PAD_NODES * 128);
    unsigned short* Sb  = (unsigned short*)w;  w += align(2ull * PAD_NODES * 128);
    (void)ws_size; (void)n_in; (void)in_sizes; (void)out_size;

    // ---- prep: deg zero + W casts + x bf16 pre-cast (R18a)
    prep_kernel<<<(DEG_CAP / 4 + 81920 + (N_NODES * 128) / 8 + 255) / 256, 256, 0, stream>>>(
        Wr0, Ws0, Wr1, Ws1, Wr2, Ws2, x, Wt0, Wt1, Wt2, Xb, deg);

    // ---- edge placement (1 edge/thread, max TLP)
    place_kernel<<<(N_EDGES + 255) / 256, 256, 0, stream>>>(src, dst, deg, esrc);

    // ---- layer 1 (bf16 Xb); T fp8, agg 8 loads/edge
    mm_kernel<128><<<dim3(PAD_NODES / 128, 2), 256, 0, stream>>>(Xb, Wt0, T, Sb);
    aggregate_kernel<128, false, true><<<N_NODES / 32, 256, 0, stream>>>(T, Sb, br0, deg, esrc, H1b, nullptr);

    // ---- layer 2; T fp8
    mm_kernel<128><<<dim3(PAD_NODES / 128, 2), 256, 0, stream>>>(H1b, Wt1, T, Sb);
    aggregate_kernel<128, false, true><<<N_NODES / 32, 256, 0, stream>>>(T, Sb, br1, deg, esrc, H2b, nullptr);

    // ---- layer 3 (bf16 T, fused log_softmax, fp32 out)
    mm_kernel<64><<<dim3(PAD_NODES / 128, 1), 256, 0, stream>>>(H2b, Wt2, T, Sb);
    aggregate_kernel<64, true, false><<<N_NODES / 32, 256, 0, stream>>>(T, Sb, br2, deg, esrc, nullptr, out);
}

// Round 9
// 199.477 us; speedup vs baseline: 1.0986x; 1.0191x over previous
//
#include <hip/hip_runtime.h>
#include <hip/hip_bf16.h>

// GraphConv x3 + ReLU + log_softmax on MI355X — bf16/MFMA pipeline.
// Per layer: [T|S] = H @ [Wr|Ws] via mfma_f32_16x16x32_bf16, then atomic-free
// aggregation (gather, fp32 accum): H' = relu(sum_j T[esrc[j]] + br + S).
// Layer 3 fuses log_softmax, fp32 out.
// LEDGER:
// R11/R16 (FAILED): place fusions — misattributed; place is ~10us.
// R13/R14: L2-residency for the gather structurally impossible; NT sub-line
//      stores bypass write-combining (regression).
// R15 (WIN 212->205.8): mm epilogue swizzled-LDS transpose -> 16B stores.
//      Partial-line global writes cost ~2x nominal.
// R17 (FAILED, insight): fp8 T with same load count gave no agg gain ->
//      agg is VMEM-op-COUNT x latency bound, not byte-bound. mm1 was the
//      hidden 52us pole (fp32 staging, occupancy 17%).
// R18 (WIN 212.5->203.3): x pre-cast bf16; (256,4); fp8 agg at 8 loads/edge.
//      Gain smaller than modeled -> remaining slack = TLP ceilings:
//      mm grid 626 = 2.4 blocks/CU; agg waves 5000 = 19.5/CU.
// R19: (a) mm tile 64x128 -> grid 1252/626, LDS 24KB, (256,6): ~2x resident
//      waves for latency-bound staging. (b) agg edge-split: 16 lanes/node =
//      2x 8-lane groups on interleaved edge slots, merged via shfl_xor(8):
//      waves 5000 -> 10000 = full 32/CU. Load count/edge unchanged.

#define N_NODES 40000
#define N_EDGES 640000
#define PAD_NODES 40064        // 313 * 128 = 626 * 64
#define DEG_CAP   40960        // int4-aligned >= N_NODES
#define ROW_CAP   64           // esrc slots per node

typedef float v4f __attribute__((ext_vector_type(4)));
typedef float v2f __attribute__((ext_vector_type(2)));
typedef short short8 __attribute__((ext_vector_type(8)));

__device__ inline unsigned short f2b(float f) {  // RNE fp32->bf16
    unsigned u = __float_as_uint(f);
    return (unsigned short)((u + 0x7fffu + ((u >> 16) & 1u)) >> 16);
}

// bf16 -> fp8 e4m3 (OCP), RNE, FTZ below 2^-6, clamp to 448 (fallback path).
__device__ inline unsigned b2f8(unsigned short us) {
    unsigned s  = ((unsigned)us >> 8) & 0x80u;
    unsigned mag = us & 0x7fffu;
    unsigned e8 = mag >> 7, m7 = mag & 0x7fu;
    unsigned out;
    if (e8 < 121u) out = 0u;                 // FTZ (< 2^-6)
    else if (e8 > 135u) out = 0x7eu;         // clamp 448
    else {
        unsigned e4 = e8 - 120u;             // 1..15
        unsigned r  = (m7 + 7u + ((m7 >> 4) & 1u)) >> 4;  // RNE 7->3 bits
        if (r == 8u) { r = 0u; e4++; }
        out = (e4 > 15u || (e4 == 15u && r > 6u)) ? 0x7eu : ((e4 << 3) | r);
    }
    return s | out;
}

// 4x f32 -> 4x fp8 packed in one dword. HW pk-cvt when available.
__device__ inline unsigned pack4_fp8(float f0, float f1, float f2, float f3) {
#if __has_builtin(__builtin_amdgcn_cvt_pk_fp8_f32)
    int w = __builtin_amdgcn_cvt_pk_fp8_f32(f0, f1, 0, false);
    w = __builtin_amdgcn_cvt_pk_fp8_f32(f2, f3, w, true);
    return (unsigned)w;
#else
    return b2f8(f2b(f0)) | (b2f8(f2b(f1)) << 8) |
           (b2f8(f2b(f2)) << 16) | (b2f8(f2b(f3)) << 24);
#endif
}

// fp8 e4m3 -> f32. HW cvt when available; manual fallback (denorms->0).
#if __has_builtin(__builtin_amdgcn_cvt_f32_fp8)
#define F8TOF(w, sel) __builtin_amdgcn_cvt_f32_fp8((int)(w), (sel))
#else
__device__ inline float f8tof_(unsigned b) {
    unsigned e = (b >> 3) & 15u;
    unsigned bits = ((b & 0x80u) << 24) |
                    (e ? (((e + 120u) << 23) | ((b & 7u) << 20)) : 0u);
    return __uint_as_float(bits);
}
#define F8TOF(w, sel) f8tof_(((unsigned)(w) >> ((sel) * 8)) & 0xffu)
#endif

// ---------------------------------------------------------------- prep
// deg zero + W transpose+cast + x -> bf16 pre-cast.
__global__ __launch_bounds__(256) void prep_kernel(const float* __restrict__ Wr0, const float* __restrict__ Ws0,
                                                   const float* __restrict__ Wr1, const float* __restrict__ Ws1,
                                                   const float* __restrict__ Wr2, const float* __restrict__ Ws2,
                                                   const float* __restrict__ x,
                                                   unsigned short* __restrict__ Wt0,
                                                   unsigned short* __restrict__ Wt1,
                                                   unsigned short* __restrict__ Wt2,
                                                   unsigned short* __restrict__ Xb,
                                                   int* __restrict__ deg) {
    int tid = blockIdx.x * 256 + threadIdx.x;
    if (tid < DEG_CAP / 4) {
        ((int4*)deg)[tid] = make_int4(0, 0, 0, 0);
        return;
    }
    int t = tid - DEG_CAP / 4;
    if (t < 32768) {
        int n = t >> 7, k = t & 127;
        const float* W = (n < 128) ? Wr0 : Ws0;
        Wt0[t] = f2b(W[k * 128 + (n & 127)]);
    } else if (t < 65536) {
        int u = t - 32768;
        int n = u >> 7, k = u & 127;
        const float* W = (n < 128) ? Wr1 : Ws1;
        Wt1[u] = f2b(W[k * 128 + (n & 127)]);
    } else if (t < 81920) {
        int u = t - 65536;
        int n = u >> 7, k = u & 127;
        const float* W = (n < 64) ? Wr2 : Ws2;
        Wt2[u] = f2b(W[k * 64 + (n & 63)]);
    } else {
        int u = t - 81920;                    // 8 floats each
        if (u < (N_NODES * 128) / 8) {
            float4 a = ((const float4*)x)[u * 2];
            float4 b = ((const float4*)x)[u * 2 + 1];
            uint4 o;
            o.x = (unsigned)f2b(a.x) | ((unsigned)f2b(a.y) << 16);
            o.y = (unsigned)f2b(a.z) | ((unsigned)f2b(a.w) << 16);
            o.z = (unsigned)f2b(b.x) | ((unsigned)f2b(b.y) << 16);
            o.w = (unsigned)f2b(b.z) | ((unsigned)f2b(b.w) << 16);
            ((uint4*)Xb)[u] = o;
        }
    }
}

// ---------------------------------------------------------------- edge placement
// 1 edge/thread (max TLP): slot = atomicAdd(deg[dst]); esrc[dst*64+slot]=src.
__global__ __launch_bounds__(256) void place_kernel(const int* __restrict__ src,
                                                    const int* __restrict__ dst,
                                                    int* __restrict__ deg,
                                                    int* __restrict__ esrc) {
    int e = blockIdx.x * 256 + threadIdx.x;
    if (e < N_EDGES) {
        int d = dst[e];
        int r = atomicAdd(&deg[d], 1);
        if (r < ROW_CAP) esrc[(size_t)d * ROW_CAP + r] = src[e];
    }
}

// ---------------------------------------------------------------- MFMA matmul
// R19 geometry: tile 64(M) x 128(N), grid (626, NB). 4 waves: wave w owns
// cols w*32..w*32+31, all 64 rows; acc[4][2]. LDS: As[64][64] + Bs[128][64]
// = 24 KB -> (256,6), grid 1252 ~ 4.9 blocks/CU (2x TLP vs 128-row tile).
// Epilogue (R15): swizzled LDS transpose -> 16B coalesced stores; zeros at
// node == N_NODES. DO=128: n0==0 writes T fp8 (in-register pk-cvt); n0==1
// writes S bf16. DO=64: T/S bf16 split at col 64.
template <int DO>
__global__ __launch_bounds__(256, 6) void mm_kernel(const unsigned short* __restrict__ Ab,
                                                    const unsigned short* __restrict__ Wt,
                                                    void* __restrict__ Tout,
                                                    unsigned short* __restrict__ S) {
    __shared__ unsigned short Smem[64 * 64 + 128 * 64];  // 24 KB
    unsigned short* As = Smem;                 // [64][64] K-half
    unsigned short* Bs = Smem + 64 * 64;       // [128][64]

    const int tid = threadIdx.x;
    const int m0  = blockIdx.x * 64;
    const int n0  = blockIdx.y * 128;

    const int wave = tid >> 6;
    const int lane = tid & 63;
    const int wc   = wave * 32;
    const int qm   = lane & 15;
    const int k8   = (lane >> 4) * 8;

    v4f acc[4][2];
#pragma unroll
    for (int i = 0; i < 4; i++)
#pragma unroll
        for (int j = 0; j < 2; j++) acc[i][j] = (v4f)(0.0f);

#pragma unroll
    for (int half = 0; half < 2; half++) {
        // ---- stage A half: 64 rows x 64 k = 512 uint4, 2/thread
#pragma unroll
        for (int i = 0; i < 2; i++) {
            int idx = i * 256 + tid;
            int row = idx >> 3, c8 = idx & 7;
            ((uint4*)As)[idx] =
                *(const uint4*)(Ab + (size_t)(m0 + row) * 128 + half * 64 + c8 * 8);
        }
        // ---- stage B half: Wt rows n0..n0+127 = 1024 uint4, 4/thread
#pragma unroll
        for (int i = 0; i < 4; i++) {
            int idx = i * 256 + tid;
            int row = idx >> 3, c8 = idx & 7;
            ((uint4*)Bs)[idx] =
                *(const uint4*)(Wt + (size_t)(n0 + row) * 128 + half * 64 + c8 * 8);
        }
        __syncthreads();

#pragma unroll
        for (int ks = 0; ks < 2; ks++) {
            short8 af[4], bf[2];
#pragma unroll
            for (int i = 0; i < 4; i++)
                af[i] = *(const short8*)(const void*)(As + (i * 16 + qm) * 64 + ks * 32 + k8);
#pragma unroll
            for (int j = 0; j < 2; j++)
                bf[j] = *(const short8*)(const void*)(Bs + (wc + j * 16 + qm) * 64 + ks * 32 + k8);
#pragma unroll
            for (int mi = 0; mi < 4; mi++)
#pragma unroll
                for (int ni = 0; ni < 2; ni++)
                    acc[mi][ni] = __builtin_amdgcn_mfma_f32_16x16x32_bf16(af[mi], bf[ni], acc[mi][ni], 0, 0, 0);
        }
        __syncthreads();
    }

    // ---- epilogue: swizzled LDS transpose (64 rows x 128 cols bf16, 16 KB).
    // C/D layout: col=lane&15, row=(lane>>4)*4+reg  [m89-verified]
#pragma unroll
    for (int mi = 0; mi < 4; mi++) {
        const int rowBase = mi * 16 + ((lane >> 4) << 2);
#pragma unroll
        for (int r = 0; r < 4; r++) {
            const int row = rowBase + r;
            const int sw  = ((row >> 2) & 3) << 4;
#pragma unroll
            for (int ni = 0; ni < 2; ni++) {
                const int c = wc + ni * 16 + qm;
                Smem[row * 128 + (c ^ sw)] = f2b(acc[mi][ni][r]);
            }
        }
    }
    __syncthreads();

    // node == N_NODES -> write ZEROS (dummy row read by aggregate pad slots).
    if (DO == 128 && n0 == 0) {
        // fp8 T: 64 rows x 8 chunks(16 dims) = 512 chunks, 2/thread
        unsigned char* T8 = (unsigned char*)Tout;
#pragma unroll
        for (int i = 0; i < 2; i++) {
            const int chunk = i * 256 + tid;
            const int row   = chunk >> 3;
            const int c0    = (chunk & 7) * 16;
            const int sw    = ((row >> 2) & 3) << 4;
            const int node  = m0 + row;
            if (node <= N_NODES) {
                uint4 v = make_uint4(0, 0, 0, 0);
                if (node < N_NODES) {
                    const unsigned short* p = Smem + row * 128 + (c0 ^ sw);
                    uint4 ha = *(const uint4*)p;
                    uint4 hb = *(const uint4*)(p + 8);
#define LOF(d) __uint_as_float((d) << 16)
#define HIF(d) __uint_as_float((d) & 0xffff0000u)
                    v.x = pack4_fp8(LOF(ha.x), HIF(ha.x), LOF(ha.y), HIF(ha.y));
                    v.y = pack4_fp8(LOF(ha.z), HIF(ha.z), LOF(ha.w), HIF(ha.w));
                    v.z = pack4_fp8(LOF(hb.x), HIF(hb.x), LOF(hb.y), HIF(hb.y));
                    v.w = pack4_fp8(LOF(hb.z), HIF(hb.z), LOF(hb.w), HIF(hb.w));
#undef LOF
#undef HIF
                }
                *(uint4*)(T8 + (size_t)node * 128 + c0) = v;
            }
        }
    } else {
        // bf16: 64 rows x 16 chunks(8 ushorts) = 1024 chunks, 4/thread
        unsigned short* T = (unsigned short*)Tout;
#pragma unroll
        for (int i = 0; i < 4; i++) {
            const int chunk = i * 256 + tid;
            const int row   = chunk >> 4;
            const int c0    = (chunk & 15) * 8;
            const int sw    = ((row >> 2) & 3) << 4;
            const int node  = m0 + row;
            if (node <= N_NODES) {
                uint4 v = make_uint4(0, 0, 0, 0);
                if (node < N_NODES)
                    v = *(const uint4*)(Smem + row * 128 + (c0 ^ sw));
                if (DO == 128) {
                    *(uint4*)(S + (size_t)node * 128 + c0) = v;   // n0==1: S
                } else {
                    if (c0 < 64) *(uint4*)(T + (size_t)node * 64 + c0) = v;
                    else         *(uint4*)(S + (size_t)node * 64 + (c0 - 64)) = v;
                }
            }
        }
    }
}

// ---------------------------------------------------------------- aggregate
// R19: 16 lanes/node = 2 edge-groups of 8 (g = slot parity at stride 16);
// groups merge partial sums via shfl_xor(8). Waves 5000 -> 10000 (32/CU).
// FP8T (layers 1-2): lane handles 16 dims, 1 uint4(16 fp8)/edge.
// Layer 3 (bf16, DO=64): lane handles 8 dims, 1 uint4(8 bf16)/edge.
// Pad slots masked in-register to dummy node 40000 (zero row).
__device__ inline void addp(v2f* a, uint4 q) {
    v2f t0 = { __uint_as_float(q.x << 16), __uint_as_float(q.x & 0xffff0000u) };
    v2f t1 = { __uint_as_float(q.y << 16), __uint_as_float(q.y & 0xffff0000u) };
    v2f t2 = { __uint_as_float(q.z << 16), __uint_as_float(q.z & 0xffff0000u) };
    v2f t3 = { __uint_as_float(q.w << 16), __uint_as_float(q.w & 0xffff0000u) };
    a[0] += t0; a[1] += t1; a[2] += t2; a[3] += t3;
}
__device__ inline void addp8w(v2f* a, unsigned w) {   // 4 fp8 -> 2 v2f
    v2f t0 = { F8TOF(w, 0), F8TOF(w, 1) };
    v2f t1 = { F8TOF(w, 2), F8TOF(w, 3) };
    a[0] += t0; a[1] += t1;
}
__device__ inline void addp16(v2f* a, uint4 q) {      // 16 fp8
    addp8w(a + 0, q.x); addp8w(a + 2, q.y);
    addp8w(a + 4, q.z); addp8w(a + 6, q.w);
}

template <int DO, bool LAST, bool FP8T>
__global__ __launch_bounds__(256) void aggregate_kernel(const void* __restrict__ Tin,
                                                        const unsigned short* __restrict__ S,
                                                        const float* __restrict__ br,
                                                        const int* __restrict__ deg,
                                                        const int* __restrict__ esrc,
                                                        unsigned short* __restrict__ Hout,
                                                        float* __restrict__ Fout) {
    constexpr int DPL = FP8T ? 16 : 8;   // dims per lane
    const int lane16 = threadIdx.x & 15;
    const int g      = lane16 >> 3;      // edge group 0/1
    const int lane   = lane16 & 7;       // lane within group
    const int n      = blockIdx.x * 16 + (threadIdx.x >> 4);

    int cnt = deg[n];
    if (cnt > ROW_CAP) cnt = ROW_CAP;    // safety (never expected)
    const int* erow = esrc + (size_t)n * ROW_CAP;
    const uint4* T4 = (const uint4*)Tin; // row = 8 uint4 both paths

    v2f acc[DPL / 2];
#pragma unroll
    for (int i = 0; i < DPL / 2; i++) acc[i] = (v2f)(0.0f);

    for (int o = g * 8; o < cnt; o += 16) {
        int4 i0 = *(const int4*)(erow + o);
        int4 i1 = *(const int4*)(erow + o + 4);
        // mask pad slots (uninitialized) -> dummy zero row (safe addressing)
        i0.x = (o + 0 < cnt) ? i0.x : N_NODES;
        i0.y = (o + 1 < cnt) ? i0.y : N_NODES;
        i0.z = (o + 2 < cnt) ? i0.z : N_NODES;
        i0.w = (o + 3 < cnt) ? i0.w : N_NODES;
        i1.x = (o + 4 < cnt) ? i1.x : N_NODES;
        i1.y = (o + 5 < cnt) ? i1.y : N_NODES;
        i1.z = (o + 6 < cnt) ? i1.z : N_NODES;
        i1.w = (o + 7 < cnt) ? i1.w : N_NODES;
        uint4 q0 = T4[(size_t)i0.x * 8 + lane];
        uint4 q1 = T4[(size_t)i0.y * 8 + lane];
        uint4 q2 = T4[(size_t)i0.z * 8 + lane];
        uint4 q3 = T4[(size_t)i0.w * 8 + lane];
        uint4 q4 = T4[(size_t)i1.x * 8 + lane];
        uint4 q5 = T4[(size_t)i1.y * 8 + lane];
        uint4 q6 = T4[(size_t)i1.z * 8 + lane];
        uint4 q7 = T4[(size_t)i1.w * 8 + lane];
        if (FP8T) {
            addp16(acc, q0); addp16(acc, q1); addp16(acc, q2); addp16(acc, q3);
            addp16(acc, q4); addp16(acc, q5); addp16(acc, q6); addp16(acc, q7);
        } else {
            addp(acc, q0); addp(acc, q1); addp(acc, q2); addp(acc, q3);
            addp(acc, q4); addp(acc, q5); addp(acc, q6); addp(acc, q7);
        }
    }

    // merge the two edge-groups (lanes l <-> l^8)
#pragma unroll
    for (int i = 0; i < DPL / 2; i++) {
        acc[i].x += __shfl_xor(acc[i].x, 8);
        acc[i].y += __shfl_xor(acc[i].y, 8);
    }

    // root term S (bf16, exact) + bias + relu (both groups compute)
    float v[DPL];
#pragma unroll
    for (int h = 0; h < DPL / 8; h++) {
        uint4 sv = ((const uint4*)S)[(size_t)n * (DO / 8) + lane * (DPL / 8) + h];
        addp(acc + h * 4, sv);
    }
#pragma unroll
    for (int j = 0; j < DPL; j++) {
        float bj = br[lane * DPL + j];
        v[j] = fmaxf(((j & 1) ? acc[j >> 1].y : acc[j >> 1].x) + bj, 0.f);
    }

    if (LAST) {
        // DO=64: dims spread over 8 lanes x 8; reduce within 8-lane group
        float m = v[0];
#pragma unroll
        for (int i = 1; i < 8; i++) m = fmaxf(m, v[i]);
#pragma unroll
        for (int off = 4; off; off >>= 1) m = fmaxf(m, __shfl_xor(m, off));
        float es = 0.f;
#pragma unroll
        for (int i = 0; i < 8; i++) es += expf(v[i] - m);
#pragma unroll
        for (int off = 4; off; off >>= 1) es += __shfl_xor(es, off);
        float lse = m + logf(es);
        if (g == 0) {
            float4 o0 = make_float4(v[0] - lse, v[1] - lse, v[2] - lse, v[3] - lse);
            float4 o1 = make_float4(v[4] - lse, v[5] - lse, v[6] - lse, v[7] - lse);
            ((float4*)Fout)[(size_t)n * 16 + lane * 2]     = o0;
            ((float4*)Fout)[(size_t)n * 16 + lane * 2 + 1] = o1;
        }
    } else if (g == 0) {
#pragma unroll
        for (int h = 0; h < DPL / 8; h++) {
            uint4 o;
            o.x = (unsigned)f2b(v[h * 8 + 0]) | ((unsigned)f2b(v[h * 8 + 1]) << 16);
            o.y = (unsigned)f2b(v[h * 8 + 2]) | ((unsigned)f2b(v[h * 8 + 3]) << 16);
            o.z = (unsigned)f2b(v[h * 8 + 4]) | ((unsigned)f2b(v[h * 8 + 5]) << 16);
            o.w = (unsigned)f2b(v[h * 8 + 6]) | ((unsigned)f2b(v[h * 8 + 7]) << 16);
            ((uint4*)Hout)[(size_t)n * (DO / 8) + lane * (DPL / 8) + h] = o;
        }
    }
}

// ---------------------------------------------------------------- launch

extern "C" void kernel_launch(void* const* d_in, const int* in_sizes, int n_in,
                              void* d_out, int out_size, void* d_ws, size_t ws_size,
                              hipStream_t stream) {
    const float* x    = (const float*)d_in[0];
    const int*   eidx = (const int*)d_in[1];   // [2, E] int32
    const float* Wr0  = (const float*)d_in[2];
    const float* br0  = (const float*)d_in[3];
    const float* Ws0  = (const float*)d_in[4];
    const float* Wr1  = (const float*)d_in[5];
    const float* br1  = (const float*)d_in[6];
    const float* Ws1  = (const float*)d_in[7];
    const float* Wr2  = (const float*)d_in[8];
    const float* br2  = (const float*)d_in[9];
    const float* Ws2  = (const float*)d_in[10];
    float* out = (float*)d_out;

    const int* src = eidx;
    const int* dst = eidx + N_EDGES;

    auto align = [](size_t v) { return (v + 255) & ~(size_t)255; };
    char* w = (char*)d_ws;
    int* deg  = (int*)w;  w += align(sizeof(int) * DEG_CAP);
    int* esrc = (int*)w;  w += align(sizeof(int) * (size_t)N_NODES * ROW_CAP);
    unsigned short* Xb  = (unsigned short*)w;  w += align(2ull * PAD_NODES * 128);
    unsigned short* H1b = (unsigned short*)w;  w += align(2ull * PAD_NODES * 128);
    unsigned short* H2b = (unsigned short*)w;  w += align(2ull * PAD_NODES * 128);
    unsigned short* Wt0 = (unsigned short*)w;  w += align(2ull * 256 * 128);
    unsigned short* Wt1 = (unsigned short*)w;  w += align(2ull * 256 * 128);
    unsigned short* Wt2 = (unsigned short*)w;  w += align(2ull * 128 * 128);
    void*           T   = (void*)w;            w += align(2ull * PAD_NODES * 128);
    unsigned short* Sb  = (unsigned short*)w;  w += align(2ull * PAD_NODES * 128);
    (void)ws_size; (void)n_in; (void)in_sizes; (void)out_size;

    // ---- prep: deg zero + W casts + x bf16 pre-cast
    prep_kernel<<<(DEG_CAP / 4 + 81920 + (N_NODES * 128) / 8 + 255) / 256, 256, 0, stream>>>(
        Wr0, Ws0, Wr1, Ws1, Wr2, Ws2, x, Wt0, Wt1, Wt2, Xb, deg);

    // ---- edge placement (1 edge/thread, max TLP)
    place_kernel<<<(N_EDGES + 255) / 256, 256, 0, stream>>>(src, dst, deg, esrc);

    // ---- layer 1 (bf16 Xb); T fp8
    mm_kernel<128><<<dim3(PAD_NODES / 64, 2), 256, 0, stream>>>(Xb, Wt0, T, Sb);
    aggregate_kernel<128, false, true><<<N_NODES / 16, 256, 0, stream>>>(T, Sb, br0, deg, esrc, H1b, nullptr);

    // ---- layer 2; T fp8
    mm_kernel<128><<<dim3(PAD_NODES / 64, 2), 256, 0, stream>>>(H1b, Wt1, T, Sb);
    aggregate_kernel<128, false, true><<<N_NODES / 16, 256, 0, stream>>>(T, Sb, br1, deg, esrc, H2b, nullptr);

    // ---- layer 3 (bf16 T, fused log_softmax, fp32 out)
    mm_kernel<64><<<dim3(PAD_NODES / 64, 1), 256, 0, stream>>>(H2b, Wt2, T, Sb);
    aggregate_kernel<64, true, false><<<N_NODES / 16, 256, 0, stream>>>(T, Sb, br2, deg, esrc, nullptr, out);
}

// Round 10
// 193.025 us; speedup vs baseline: 1.1354x; 1.0334x over previous
//
#include <hip/hip_runtime.h>
#include <hip/hip_bf16.h>

// GraphConv x3 + ReLU + log_softmax on MI355X — bf16/MFMA pipeline.
// LEDGER (keep):
// R11/R16: place fusions FAILED (misattribution; place ~10us). R12 neutral.
// R13/R14: L2-residency for gather impossible (no split fits 4MB at >=1
//      line/edge); NT sub-line stores bypass write-combining.
// R15 (WIN): mm epilogue swizzled-LDS transpose -> 16B coalesced stores;
//      partial-line global writes cost ~2x nominal.
// R17 (insight): agg is VMEM-op-COUNT x latency bound, not byte-bound.
// R18 (WIN): x pre-cast bf16; fp8 T at 8 loads/edge.
// R19 (WIN +4 only): 2x TLP on mm+agg gave little -> both at the per-CU
//      MSHR cap. Per-kernel levers exhausted; remaining cost is STRUCTURAL
//      (8 serial dispatches; gather runs with MFMA idle and vice versa).
// R20: agg fused as NEXT mm's prologue. mm block owns 64 rows x FULL 256
//      cols (no y-split -> no duplicated gather): computes H rows in-reg
//      from T_prev/S_prev (previous dispatch), stages to As, MFMAs.
//      H1/H2 never hit HBM (-40MB); dispatches 8->6; co-resident blocks
//      pipeline gather vs MFMA phases. As/Bs XOR chunk-swizzle kills the
//      16-way b128 read conflict (R7 PMC: 2.08M SQ_LDS_BANK_CONFLICT).

#define N_NODES 40000
#define N_EDGES 640000
#define PAD_NODES 40064        // 626 * 64
#define DEG_CAP   40960        // int4-aligned >= N_NODES
#define ROW_CAP   64           // esrc slots per node

typedef float v4f __attribute__((ext_vector_type(4)));
typedef float v2f __attribute__((ext_vector_type(2)));
typedef short short8 __attribute__((ext_vector_type(8)));

__device__ inline unsigned short f2b(float f) {  // RNE fp32->bf16
    unsigned u = __float_as_uint(f);
    return (unsigned short)((u + 0x7fffu + ((u >> 16) & 1u)) >> 16);
}

// bf16 -> fp8 e4m3 (OCP), RNE, FTZ below 2^-6, clamp 448 (fallback path).
__device__ inline unsigned b2f8(unsigned short us) {
    unsigned s  = ((unsigned)us >> 8) & 0x80u;
    unsigned mag = us & 0x7fffu;
    unsigned e8 = mag >> 7, m7 = mag & 0x7fu;
    unsigned out;
    if (e8 < 121u) out = 0u;
    else if (e8 > 135u) out = 0x7eu;
    else {
        unsigned e4 = e8 - 120u;
        unsigned r  = (m7 + 7u + ((m7 >> 4) & 1u)) >> 4;
        if (r == 8u) { r = 0u; e4++; }
        out = (e4 > 15u || (e4 == 15u && r > 6u)) ? 0x7eu : ((e4 << 3) | r);
    }
    return s | out;
}

__device__ inline unsigned pack4_fp8(float f0, float f1, float f2, float f3) {
#if __has_builtin(__builtin_amdgcn_cvt_pk_fp8_f32)
    int w = __builtin_amdgcn_cvt_pk_fp8_f32(f0, f1, 0, false);
    w = __builtin_amdgcn_cvt_pk_fp8_f32(f2, f3, w, true);
    return (unsigned)w;
#else
    return b2f8(f2b(f0)) | (b2f8(f2b(f1)) << 8) |
           (b2f8(f2b(f2)) << 16) | (b2f8(f2b(f3)) << 24);
#endif
}

#if __has_builtin(__builtin_amdgcn_cvt_f32_fp8)
#define F8TOF(w, sel) __builtin_amdgcn_cvt_f32_fp8((int)(w), (sel))
#else
__device__ inline float f8tof_(unsigned b) {
    unsigned e = (b >> 3) & 15u;
    unsigned bits = ((b & 0x80u) << 24) |
                    (e ? (((e + 120u) << 23) | ((b & 7u) << 20)) : 0u);
    return __uint_as_float(bits);
}
#define F8TOF(w, sel) f8tof_(((unsigned)(w) >> ((sel) * 8)) & 0xffu)
#endif

__device__ inline void addp(v2f* a, uint4 q) {       // 8 bf16
    v2f t0 = { __uint_as_float(q.x << 16), __uint_as_float(q.x & 0xffff0000u) };
    v2f t1 = { __uint_as_float(q.y << 16), __uint_as_float(q.y & 0xffff0000u) };
    v2f t2 = { __uint_as_float(q.z << 16), __uint_as_float(q.z & 0xffff0000u) };
    v2f t3 = { __uint_as_float(q.w << 16), __uint_as_float(q.w & 0xffff0000u) };
    a[0] += t0; a[1] += t1; a[2] += t2; a[3] += t3;
}
__device__ inline void addp8w(v2f* a, unsigned w) {  // 4 fp8
    v2f t0 = { F8TOF(w, 0), F8TOF(w, 1) };
    v2f t1 = { F8TOF(w, 2), F8TOF(w, 3) };
    a[0] += t0; a[1] += t1;
}
__device__ inline void addp16(v2f* a, uint4 q) {     // 16 fp8
    addp8w(a + 0, q.x); addp8w(a + 2, q.y);
    addp8w(a + 4, q.z); addp8w(a + 6, q.w);
}

// ---------------------------------------------------------------- prep
__global__ __launch_bounds__(256) void prep_kernel(const float* __restrict__ Wr0, const float* __restrict__ Ws0,
                                                   const float* __restrict__ Wr1, const float* __restrict__ Ws1,
                                                   const float* __restrict__ Wr2, const float* __restrict__ Ws2,
                                                   const float* __restrict__ x,
                                                   unsigned short* __restrict__ Wt0,
                                                   unsigned short* __restrict__ Wt1,
                                                   unsigned short* __restrict__ Wt2,
                                                   unsigned short* __restrict__ Xb,
                                                   int* __restrict__ deg) {
    int tid = blockIdx.x * 256 + threadIdx.x;
    if (tid < DEG_CAP / 4) {
        ((int4*)deg)[tid] = make_int4(0, 0, 0, 0);
        return;
    }
    int t = tid - DEG_CAP / 4;
    if (t < 32768) {
        int n = t >> 7, k = t & 127;
        const float* W = (n < 128) ? Wr0 : Ws0;
        Wt0[t] = f2b(W[k * 128 + (n & 127)]);
    } else if (t < 65536) {
        int u = t - 32768;
        int n = u >> 7, k = u & 127;
        const float* W = (n < 128) ? Wr1 : Ws1;
        Wt1[u] = f2b(W[k * 128 + (n & 127)]);
    } else if (t < 81920) {
        int u = t - 65536;
        int n = u >> 7, k = u & 127;
        const float* W = (n < 64) ? Wr2 : Ws2;
        Wt2[u] = f2b(W[k * 64 + (n & 63)]);
    } else {
        int u = t - 81920;                    // 8 floats each
        if (u < (N_NODES * 128) / 8) {
            float4 a = ((const float4*)x)[u * 2];
            float4 b = ((const float4*)x)[u * 2 + 1];
            uint4 o;
            o.x = (unsigned)f2b(a.x) | ((unsigned)f2b(a.y) << 16);
            o.y = (unsigned)f2b(a.z) | ((unsigned)f2b(a.w) << 16);
            o.z = (unsigned)f2b(b.x) | ((unsigned)f2b(b.y) << 16);
            o.w = (unsigned)f2b(b.z) | ((unsigned)f2b(b.w) << 16);
            ((uint4*)Xb)[u] = o;
        }
    }
}

// ---------------------------------------------------------------- edge placement
__global__ __launch_bounds__(256) void place_kernel(const int* __restrict__ src,
                                                    const int* __restrict__ dst,
                                                    int* __restrict__ deg,
                                                    int* __restrict__ esrc) {
    int e = blockIdx.x * 256 + threadIdx.x;
    if (e < N_EDGES) {
        int d = dst[e];
        int r = atomicAdd(&deg[d], 1);
        if (r < ROW_CAP) esrc[(size_t)d * ROW_CAP + r] = src[e];
    }
}

// ---------------------------------------------------------------- fused mm
// Block b: rows b*64..+63, ALL NB=2*DO output cols (T = cols 0..DO-1,
// S = cols DO..NB-1). AGG: prologue computes H rows in-register
// (fp8 T_prev gather + S_prev + bias + relu), stages to As. !AGG: stage
// bf16 Ain. As[64][128] (16KB) chunk-swizzled c^(r&7); Bs[NB][64] per
// K-half (32/16KB) same swizzle. Epilogue: acc -> Es(=Bs region) with R15
// sw-XOR -> 16B coalesced stores; T fp8 (DO=128) or bf16 (DO=64).
// node==N_NODES row forced to zeros (dummy row for pad-slot gathers).
template <int DO, bool AGG>
__global__ __launch_bounds__(256, 3) void mmf_kernel(const void* __restrict__ Ain,
                                                     const unsigned short* __restrict__ Sprev,
                                                     const float* __restrict__ brp,
                                                     const int* __restrict__ deg,
                                                     const int* __restrict__ esrc,
                                                     const unsigned short* __restrict__ Wt,
                                                     void* __restrict__ Tout,
                                                     unsigned short* __restrict__ Sout) {
    constexpr int NB  = 2 * DO;          // total output cols (256 or 128)
    constexpr int NBW = NB / 4;          // cols per wave (64 or 32)
    constexpr int CF  = NBW / 16;        // col frags per wave (4 or 2)

    __shared__ unsigned short AsMem[64 * 128];   // 16 KB
    __shared__ unsigned short BsMem[NB * 64];    // 32 KB (DO=128) / 16 KB
    uint4* As4 = (uint4*)AsMem;
    uint4* Bs4 = (uint4*)BsMem;

    const int tid  = threadIdx.x;
    const int m0   = blockIdx.x * 64;
    const int wave = tid >> 6;
    const int lane = tid & 63;
    const int qm   = lane & 15;
    const int hi   = lane >> 4;          // 0..3
    const int wcb  = wave * NBW;

    // ---- stage B half 0 (issue early; coalesced, L2-hot W)
#pragma unroll
    for (int i = 0; i < NB * 8 / 256; i++) {
        int idx = i * 256 + tid;
        int row = idx >> 3, c8 = idx & 7;
        Bs4[row * 8 + (c8 ^ (row & 7))] =
            *(const uint4*)(Wt + (size_t)row * 128 + c8 * 8);
    }

    // ---- A: aggregate prologue or global stage
    if (AGG) {
        const int noderow = tid >> 2;    // 0..63
        const int lane4   = tid & 3;     // 32 dims each
        const int n       = m0 + noderow;
        if (n < N_NODES) {
            int cnt = deg[n];
            if (cnt > ROW_CAP) cnt = ROW_CAP;
            const int* erow = esrc + (size_t)n * ROW_CAP;
            const uint4* T8 = (const uint4*)Ain;  // fp8 row = 8 uint4
            v2f acc[16];
#pragma unroll
            for (int i = 0; i < 16; i++) acc[i] = (v2f)(0.0f);
            for (int o = 0; o < cnt; o += 4) {
                int4 i0 = *(const int4*)(erow + o);
                i0.x = (o + 0 < cnt) ? i0.x : N_NODES;
                i0.y = (o + 1 < cnt) ? i0.y : N_NODES;
                i0.z = (o + 2 < cnt) ? i0.z : N_NODES;
                i0.w = (o + 3 < cnt) ? i0.w : N_NODES;
                size_t b0 = (size_t)i0.x * 8 + lane4 * 2;
                size_t b1 = (size_t)i0.y * 8 + lane4 * 2;
                size_t b2 = (size_t)i0.z * 8 + lane4 * 2;
                size_t b3 = (size_t)i0.w * 8 + lane4 * 2;
                uint4 qa0 = T8[b0], qb0 = T8[b0 + 1];
                uint4 qa1 = T8[b1], qb1 = T8[b1 + 1];
                uint4 qa2 = T8[b2], qb2 = T8[b2 + 1];
                uint4 qa3 = T8[b3], qb3 = T8[b3 + 1];
                addp16(acc, qa0); addp16(acc + 8, qb0);
                addp16(acc, qa1); addp16(acc + 8, qb1);
                addp16(acc, qa2); addp16(acc + 8, qb2);
                addp16(acc, qa3); addp16(acc + 8, qb3);
            }
            // + S (bf16 exact) + bias, relu, pack to As
#pragma unroll
            for (int h = 0; h < 4; h++) {
                uint4 sv = ((const uint4*)Sprev)[(size_t)n * 16 + lane4 * 4 + h];
                addp(acc + h * 4, sv);
            }
#pragma unroll
            for (int h = 0; h < 4; h++) {
                float vv[8];
#pragma unroll
                for (int j = 0; j < 8; j++) {
                    int d = h * 8 + j;
                    float bj = brp[lane4 * 32 + d];
                    vv[j] = fmaxf(((d & 1) ? acc[d >> 1].y : acc[d >> 1].x) + bj, 0.f);
                }
                uint4 o;
                o.x = (unsigned)f2b(vv[0]) | ((unsigned)f2b(vv[1]) << 16);
                o.y = (unsigned)f2b(vv[2]) | ((unsigned)f2b(vv[3]) << 16);
                o.z = (unsigned)f2b(vv[4]) | ((unsigned)f2b(vv[5]) << 16);
                o.w = (unsigned)f2b(vv[6]) | ((unsigned)f2b(vv[7]) << 16);
                As4[noderow * 16 + ((lane4 * 4 + h) ^ (noderow & 7))] = o;
            }
        } else {
            uint4 z = make_uint4(0, 0, 0, 0);
#pragma unroll
            for (int h = 0; h < 4; h++)
                As4[noderow * 16 + ((lane4 * 4 + h) ^ (noderow & 7))] = z;
        }
    } else {
        const unsigned short* Ab = (const unsigned short*)Ain;
#pragma unroll
        for (int i = 0; i < 4; i++) {
            int idx = i * 256 + tid;             // 0..1023
            int row = idx >> 4, c = idx & 15;
            int gr = m0 + row;
            if (gr > N_NODES - 1) gr = N_NODES - 1;  // pad clamp
            As4[row * 16 + (c ^ (row & 7))] =
                *(const uint4*)(Ab + (size_t)gr * 128 + c * 8);
        }
    }
    __syncthreads();

    // ---- MFMA: K=128 in 2 halves; Bs restaged between halves
    v4f acc[4][CF];
#pragma unroll
    for (int i = 0; i < 4; i++)
#pragma unroll
        for (int j = 0; j < CF; j++) acc[i][j] = (v4f)(0.0f);

#pragma unroll
    for (int half = 0; half < 2; half++) {
        if (half == 1) {
            __syncthreads();
#pragma unroll
            for (int i = 0; i < NB * 8 / 256; i++) {
                int idx = i * 256 + tid;
                int row = idx >> 3, c8 = idx & 7;
                Bs4[row * 8 + (c8 ^ (row & 7))] =
                    *(const uint4*)(Wt + (size_t)row * 128 + 64 + c8 * 8);
            }
            __syncthreads();
        }
#pragma unroll
        for (int ks = 0; ks < 2; ks++) {
            short8 af[4], bf[CF];
#pragma unroll
            for (int mi = 0; mi < 4; mi++) {
                const int r  = mi * 16 + qm;
                const int ca = half * 8 + ks * 4 + hi;
                af[mi] = *(const short8*)&As4[r * 16 + (ca ^ (r & 7))];
            }
#pragma unroll
            for (int ni = 0; ni < CF; ni++) {
                const int rb = wcb + ni * 16 + qm;
                const int cb = ks * 4 + hi;
                bf[ni] = *(const short8*)&Bs4[rb * 8 + (cb ^ (rb & 7))];
            }
#pragma unroll
            for (int mi = 0; mi < 4; mi++)
#pragma unroll
                for (int ni = 0; ni < CF; ni++)
                    acc[mi][ni] = __builtin_amdgcn_mfma_f32_16x16x32_bf16(af[mi], bf[ni], acc[mi][ni], 0, 0, 0);
        }
    }
    __syncthreads();

    // ---- epilogue: acc -> Es (=Bs region) bf16 [64][NB], R15 sw-XOR
    unsigned short* Es = BsMem;
#pragma unroll
    for (int mi = 0; mi < 4; mi++) {
        const int rowBase = mi * 16 + (hi << 2);
#pragma unroll
        for (int r = 0; r < 4; r++) {
            const int row = rowBase + r;
            const int sw  = ((row >> 2) & 3) << 4;
#pragma unroll
            for (int ni = 0; ni < CF; ni++) {
                const int c = wcb + ni * 16 + qm;
                Es[row * NB + (c ^ sw)] = f2b(acc[mi][ni][r]);
            }
        }
    }
    __syncthreads();

    if (DO == 128) {
        // T fp8: 64 rows x 8 chunks(16 dims, cols 0..127) = 512, 2/thread
        unsigned char* T8o = (unsigned char*)Tout;
#pragma unroll
        for (int i = 0; i < 2; i++) {
            const int chunk = i * 256 + tid;
            const int row   = chunk >> 3;
            const int c0    = (chunk & 7) * 16;
            const int sw    = ((row >> 2) & 3) << 4;
            const int node  = m0 + row;
            if (node <= N_NODES) {
                uint4 v = make_uint4(0, 0, 0, 0);
                if (node < N_NODES) {
                    const unsigned short* p = Es + row * 256 + (c0 ^ sw);
                    uint4 ha = *(const uint4*)p;
                    uint4 hb = *(const uint4*)(p + 8);
#define LOF(d) __uint_as_float((d) << 16)
#define HIF(d) __uint_as_float((d) & 0xffff0000u)
                    v.x = pack4_fp8(LOF(ha.x), HIF(ha.x), LOF(ha.y), HIF(ha.y));
                    v.y = pack4_fp8(LOF(ha.z), HIF(ha.z), LOF(ha.w), HIF(ha.w));
                    v.z = pack4_fp8(LOF(hb.x), HIF(hb.x), LOF(hb.y), HIF(hb.y));
                    v.w = pack4_fp8(LOF(hb.z), HIF(hb.z), LOF(hb.w), HIF(hb.w));
#undef LOF
#undef HIF
                }
                *(uint4*)(T8o + (size_t)node * 128 + c0) = v;
            }
        }
        // S bf16: cols 128..255 = 1024 16B chunks, 4/thread
#pragma unroll
        for (int i = 0; i < 4; i++) {
            const int chunk = i * 256 + tid;
            const int row   = chunk >> 4;
            const int c0    = 128 + (chunk & 15) * 8;
            const int sw    = ((row >> 2) & 3) << 4;
            const int node  = m0 + row;
            if (node <= N_NODES) {
                uint4 v = make_uint4(0, 0, 0, 0);
                if (node < N_NODES)
                    v = *(const uint4*)(Es + row * 256 + (c0 ^ sw));
                *(uint4*)(Sout + (size_t)node * 128 + (c0 - 128)) = v;
            }
        }
    } else {
        // DO=64: T bf16 cols 0..63, S bf16 cols 64..127; 1024 chunks
        unsigned short* Tb = (unsigned short*)Tout;
#pragma unroll
        for (int i = 0; i < 4; i++) {
            const int chunk = i * 256 + tid;
            const int row   = chunk >> 4;
            const int c0    = (chunk & 15) * 8;
            const int sw    = ((row >> 2) & 3) << 4;
            const int node  = m0 + row;
            if (node <= N_NODES) {
                uint4 v = make_uint4(0, 0, 0, 0);
                if (node < N_NODES)
                    v = *(const uint4*)(Es + row * 128 + (c0 ^ sw));
                if (c0 < 64) *(uint4*)(Tb + (size_t)node * 64 + c0) = v;
                else         *(uint4*)(Sout + (size_t)node * 64 + (c0 - 64)) = v;
            }
        }
    }
}

// ---------------------------------------------------------------- final aggregate
// Layer 3 agg + log_softmax (R19 structure): 16 lanes/node = 2 edge groups
// of 8, merged via shfl_xor(8); bf16 T row = 8 uint4.
__global__ __launch_bounds__(256) void agg_last_kernel(const unsigned short* __restrict__ T,
                                                       const unsigned short* __restrict__ S,
                                                       const float* __restrict__ br,
                                                       const int* __restrict__ deg,
                                                       const int* __restrict__ esrc,
                                                       float* __restrict__ Fout) {
    const int lane16 = threadIdx.x & 15;
    const int g      = lane16 >> 3;
    const int lane   = lane16 & 7;
    const int n      = blockIdx.x * 16 + (threadIdx.x >> 4);

    int cnt = deg[n];
    if (cnt > ROW_CAP) cnt = ROW_CAP;
    const int* erow = esrc + (size_t)n * ROW_CAP;
    const uint4* T4 = (const uint4*)T;

    v2f acc[4];
    acc[0] = (v2f)(0.0f); acc[1] = (v2f)(0.0f);
    acc[2] = (v2f)(0.0f); acc[3] = (v2f)(0.0f);

    for (int o = g * 8; o < cnt; o += 16) {
        int4 i0 = *(const int4*)(erow + o);
        int4 i1 = *(const int4*)(erow + o + 4);
        i0.x = (o + 0 < cnt) ? i0.x : N_NODES;
        i0.y = (o + 1 < cnt) ? i0.y : N_NODES;
        i0.z = (o + 2 < cnt) ? i0.z : N_NODES;
        i0.w = (o + 3 < cnt) ? i0.w : N_NODES;
        i1.x = (o + 4 < cnt) ? i1.x : N_NODES;
        i1.y = (o + 5 < cnt) ? i1.y : N_NODES;
        i1.z = (o + 6 < cnt) ? i1.z : N_NODES;
        i1.w = (o + 7 < cnt) ? i1.w : N_NODES;
        uint4 q0 = T4[(size_t)i0.x * 8 + lane];
        uint4 q1 = T4[(size_t)i0.y * 8 + lane];
        uint4 q2 = T4[(size_t)i0.z * 8 + lane];
        uint4 q3 = T4[(size_t)i0.w * 8 + lane];
        uint4 q4 = T4[(size_t)i1.x * 8 + lane];
        uint4 q5 = T4[(size_t)i1.y * 8 + lane];
        uint4 q6 = T4[(size_t)i1.z * 8 + lane];
        uint4 q7 = T4[(size_t)i1.w * 8 + lane];
        addp(acc, q0); addp(acc, q1); addp(acc, q2); addp(acc, q3);
        addp(acc, q4); addp(acc, q5); addp(acc, q6); addp(acc, q7);
    }
#pragma unroll
    for (int i = 0; i < 4; i++) {
        acc[i].x += __shfl_xor(acc[i].x, 8);
        acc[i].y += __shfl_xor(acc[i].y, 8);
    }

    uint4 sv = ((const uint4*)S)[(size_t)n * 8 + lane];
    addp(acc, sv);
    const float4 b0 = ((const float4*)br)[lane * 2];
    const float4 b1 = ((const float4*)br)[lane * 2 + 1];

    float v[8];
    v[0] = fmaxf(acc[0].x + b0.x, 0.f); v[1] = fmaxf(acc[0].y + b0.y, 0.f);
    v[2] = fmaxf(acc[1].x + b0.z, 0.f); v[3] = fmaxf(acc[1].y + b0.w, 0.f);
    v[4] = fmaxf(acc[2].x + b1.x, 0.f); v[5] = fmaxf(acc[2].y + b1.y, 0.f);
    v[6] = fmaxf(acc[3].x + b1.z, 0.f); v[7] = fmaxf(acc[3].y + b1.w, 0.f);

    float m = v[0];
#pragma unroll
    for (int i = 1; i < 8; i++) m = fmaxf(m, v[i]);
#pragma unroll
    for (int off = 4; off; off >>= 1) m = fmaxf(m, __shfl_xor(m, off));
    float es = 0.f;
#pragma unroll
    for (int i = 0; i < 8; i++) es += expf(v[i] - m);
#pragma unroll
    for (int off = 4; off; off >>= 1) es += __shfl_xor(es, off);
    float lse = m + logf(es);
    if (g == 0) {
        float4 o0 = make_float4(v[0] - lse, v[1] - lse, v[2] - lse, v[3] - lse);
        float4 o1 = make_float4(v[4] - lse, v[5] - lse, v[6] - lse, v[7] - lse);
        ((float4*)Fout)[(size_t)n * 16 + lane * 2]     = o0;
        ((float4*)Fout)[(size_t)n * 16 + lane * 2 + 1] = o1;
    }
}

// ---------------------------------------------------------------- launch

extern "C" void kernel_launch(void* const* d_in, const int* in_sizes, int n_in,
                              void* d_out, int out_size, void* d_ws, size_t ws_size,
                              hipStream_t stream) {
    const float* x    = (const float*)d_in[0];
    const int*   eidx = (const int*)d_in[1];   // [2, E] int32
    const float* Wr0  = (const float*)d_in[2];
    const float* br0  = (const float*)d_in[3];
    const float* Ws0  = (const float*)d_in[4];
    const float* Wr1  = (const float*)d_in[5];
    const float* br1  = (const float*)d_in[6];
    const float* Ws1  = (const float*)d_in[7];
    const float* Wr2  = (const float*)d_in[8];
    const float* br2  = (const float*)d_in[9];
    const float* Ws2  = (const float*)d_in[10];
    float* out = (float*)d_out;

    const int* src = eidx;
    const int* dst = eidx + N_EDGES;

    auto align = [](size_t v) { return (v + 255) & ~(size_t)255; };
    char* w = (char*)d_ws;
    int* deg  = (int*)w;  w += align(sizeof(int) * DEG_CAP);
    int* esrc = (int*)w;  w += align(sizeof(int) * (size_t)N_NODES * ROW_CAP);
    unsigned short* Xb  = (unsigned short*)w;  w += align(2ull * PAD_NODES * 128);
    unsigned short* Wt0 = (unsigned short*)w;  w += align(2ull * 256 * 128);
    unsigned short* Wt1 = (unsigned short*)w;  w += align(2ull * 256 * 128);
    unsigned short* Wt2 = (unsigned short*)w;  w += align(2ull * 128 * 128);
    void* T_a = (void*)w;                      w += align(2ull * PAD_NODES * 64);  // fp8 128 / bf16 64
    void* T_b = (void*)w;                      w += align(2ull * PAD_NODES * 64);
    unsigned short* S_a = (unsigned short*)w;  w += align(2ull * PAD_NODES * 128);
    unsigned short* S_b = (unsigned short*)w;  w += align(2ull * PAD_NODES * 128);
    (void)ws_size; (void)n_in; (void)in_sizes; (void)out_size;

    // ---- prep: deg zero + W casts + x bf16 pre-cast
    prep_kernel<<<(DEG_CAP / 4 + 81920 + (N_NODES * 128) / 8 + 255) / 256, 256, 0, stream>>>(
        Wr0, Ws0, Wr1, Ws1, Wr2, Ws2, x, Wt0, Wt1, Wt2, Xb, deg);

    // ---- edge placement
    place_kernel<<<(N_EDGES + 255) / 256, 256, 0, stream>>>(src, dst, deg, esrc);

    // ---- layer 1: mm only (Xb -> T_a fp8, S_a)
    mmf_kernel<128, false><<<PAD_NODES / 64, 256, 0, stream>>>(
        Xb, nullptr, nullptr, nullptr, nullptr, Wt0, T_a, S_a);

    // ---- layer 2: agg(L1) prologue + mm (T_a,S_a -> T_b fp8, S_b)
    mmf_kernel<128, true><<<PAD_NODES / 64, 256, 0, stream>>>(
        T_a, S_a, br0, deg, esrc, Wt1, T_b, S_b);

    // ---- layer 3: agg(L2) prologue + mm (T_b,S_b -> T_a bf16[64], S_a[64])
    mmf_kernel<64, true><<<PAD_NODES / 64, 256, 0, stream>>>(
        T_b, S_b, br1, deg, esrc, Wt2, T_a, S_a);

    // ---- final aggregate + log_softmax
    agg_last_kernel<<<N_NODES / 16, 256, 0, stream>>>(
        (const unsigned short*)T_a, S_a, br2, deg, esrc, out);
}

// Round 11
// 185.039 us; speedup vs baseline: 1.1843x; 1.0432x over previous
//
#include <hip/hip_runtime.h>
#include <hip/hip_bf16.h>

// GraphConv x3 + ReLU + log_softmax on MI355X — bf16/MFMA pipeline.
// LEDGER (keep):
// R11/R16/R12: place fusion/spreading dead ends — place ~10us; overlapping
//      two VMEM-latency-bound phases gains NOTHING (global VMEM-op currency).
// R13/R14: L2-residency for gather impossible; NT sub-line stores bad.
// R15 (WIN): swizzled-LDS transpose epilogue -> 16B stores (partial-line
//      writes cost 2x). R17 (insight): gather is VMEM-op-COUNT x latency
//      bound. R18 (WIN): fp8 T at 8 loads/edge (1 line). R19 (WIN +4):
//      TLP beyond MSHR cap adds little.
// R20 (WIN 199.5->193): agg fused as next mm's prologue (H never hits HBM,
//      dispatches 8->6). Gain partial: 48KB/3-blocks-CU => all 626 blocks
//      co-resident in ONE round -> gather and MFMA phases globally
//      phase-locked, no cross-block overlap.
// R21: (a) Xb dropped — mmf1 stages fp32 x directly (-1.9M VMEM ops, -1
//      dependency); (b) prep+place merged into one LDS-free kernel (deg via
//      memsetAsync; place at full occupancy — no R11 LDS trap); (c) mmf
//      rows 64->32, grid 1252 at (256,3): 1.63 rounds -> later-round
//      gathers overlap earlier-round MFMAs.

#define N_NODES 40000
#define N_EDGES 640000
#define PAD_NODES 40064        // 1252 * 32
#define DEG_CAP   40960
#define ROW_CAP   64           // esrc slots per node

typedef float v4f __attribute__((ext_vector_type(4)));
typedef float v2f __attribute__((ext_vector_type(2)));
typedef short short8 __attribute__((ext_vector_type(8)));

__device__ inline unsigned short f2b(float f) {  // RNE fp32->bf16
    unsigned u = __float_as_uint(f);
    return (unsigned short)((u + 0x7fffu + ((u >> 16) & 1u)) >> 16);
}

// bf16 -> fp8 e4m3 (OCP), RNE, FTZ below 2^-6, clamp 448 (fallback path).
__device__ inline unsigned b2f8(unsigned short us) {
    unsigned s  = ((unsigned)us >> 8) & 0x80u;
    unsigned mag = us & 0x7fffu;
    unsigned e8 = mag >> 7, m7 = mag & 0x7fu;
    unsigned out;
    if (e8 < 121u) out = 0u;
    else if (e8 > 135u) out = 0x7eu;
    else {
        unsigned e4 = e8 - 120u;
        unsigned r  = (m7 + 7u + ((m7 >> 4) & 1u)) >> 4;
        if (r == 8u) { r = 0u; e4++; }
        out = (e4 > 15u || (e4 == 15u && r > 6u)) ? 0x7eu : ((e4 << 3) | r);
    }
    return s | out;
}

__device__ inline unsigned pack4_fp8(float f0, float f1, float f2, float f3) {
#if __has_builtin(__builtin_amdgcn_cvt_pk_fp8_f32)
    int w = __builtin_amdgcn_cvt_pk_fp8_f32(f0, f1, 0, false);
    w = __builtin_amdgcn_cvt_pk_fp8_f32(f2, f3, w, true);
    return (unsigned)w;
#else
    return b2f8(f2b(f0)) | (b2f8(f2b(f1)) << 8) |
           (b2f8(f2b(f2)) << 16) | (b2f8(f2b(f3)) << 24);
#endif
}

#if __has_builtin(__builtin_amdgcn_cvt_f32_fp8)
#define F8TOF(w, sel) __builtin_amdgcn_cvt_f32_fp8((int)(w), (sel))
#else
__device__ inline float f8tof_(unsigned b) {
    unsigned e = (b >> 3) & 15u;
    unsigned bits = ((b & 0x80u) << 24) |
                    (e ? (((e + 120u) << 23) | ((b & 7u) << 20)) : 0u);
    return __uint_as_float(bits);
}
#define F8TOF(w, sel) f8tof_(((unsigned)(w) >> ((sel) * 8)) & 0xffu)
#endif

__device__ inline void addp(v2f* a, uint4 q) {       // 8 bf16
    v2f t0 = { __uint_as_float(q.x << 16), __uint_as_float(q.x & 0xffff0000u) };
    v2f t1 = { __uint_as_float(q.y << 16), __uint_as_float(q.y & 0xffff0000u) };
    v2f t2 = { __uint_as_float(q.z << 16), __uint_as_float(q.z & 0xffff0000u) };
    v2f t3 = { __uint_as_float(q.w << 16), __uint_as_float(q.w & 0xffff0000u) };
    a[0] += t0; a[1] += t1; a[2] += t2; a[3] += t3;
}
__device__ inline void addp8w(v2f* a, unsigned w) {  // 4 fp8
    v2f t0 = { F8TOF(w, 0), F8TOF(w, 1) };
    v2f t1 = { F8TOF(w, 2), F8TOF(w, 3) };
    a[0] += t0; a[1] += t1;
}
__device__ inline void addp16(v2f* a, uint4 q) {     // 16 fp8 -> a[0..7]
    addp8w(a + 0, q.x); addp8w(a + 2, q.y);
    addp8w(a + 4, q.z); addp8w(a + 6, q.w);
}

// ---------------------------------------------------------------- prep+place
// LDS-free fused kernel (R21b): blocks [0,2500) place edges (full 32-wave
// occupancy — no LDS trap); blocks [2500,2820) do W casts. deg zeroed by
// hipMemsetAsync before this kernel.
__global__ __launch_bounds__(256) void prep_place_kernel(const int* __restrict__ src,
                                                         const int* __restrict__ dst,
                                                         int* __restrict__ deg,
                                                         int* __restrict__ esrc,
                                                         const float* __restrict__ Wr0, const float* __restrict__ Ws0,
                                                         const float* __restrict__ Wr1, const float* __restrict__ Ws1,
                                                         const float* __restrict__ Wr2, const float* __restrict__ Ws2,
                                                         unsigned short* __restrict__ Wt0,
                                                         unsigned short* __restrict__ Wt1,
                                                         unsigned short* __restrict__ Wt2) {
    const int bid = blockIdx.x;
    if (bid < 2500) {
        int e = bid * 256 + threadIdx.x;
        if (e < N_EDGES) {
            int d = dst[e];
            int r = atomicAdd(&deg[d], 1);
            if (r < ROW_CAP) esrc[(size_t)d * ROW_CAP + r] = src[e];
        }
    } else {
        int t = (bid - 2500) * 256 + threadIdx.x;   // 0..81919
        if (t < 32768) {
            int n = t >> 7, k = t & 127;
            const float* W = (n < 128) ? Wr0 : Ws0;
            Wt0[t] = f2b(W[k * 128 + (n & 127)]);
        } else if (t < 65536) {
            int u = t - 32768;
            int n = u >> 7, k = u & 127;
            const float* W = (n < 128) ? Wr1 : Ws1;
            Wt1[u] = f2b(W[k * 128 + (n & 127)]);
        } else if (t < 81920) {
            int u = t - 65536;
            int n = u >> 7, k = u & 127;
            const float* W = (n < 64) ? Wr2 : Ws2;
            Wt2[u] = f2b(W[k * 64 + (n & 63)]);
        }
    }
}

// ---------------------------------------------------------------- fused mm
// R21c geometry: block owns 32 rows x full NB=2*DO cols; grid 1252;
// LDS = As[32][128] 8KB + Bs[NB][64] 32/16KB; (256,3) -> 768 resident of
// 1252 blocks = 1.63 rounds (cross-round gather/MFMA mixing).
// AGG: 8 lanes/node x 16 dims, 1 uint4/edge/lane fp8 gather (8 loads/edge).
// F32: stage A from fp32 x directly (R21a). Epilogue (R15): swizzled Es
// (=Bs region) -> 16B coalesced stores; node==N_NODES row forced zeros.
template <int DO, bool AGG, bool F32>
__global__ __launch_bounds__(256, 3) void mmf_kernel(const void* __restrict__ Ain,
                                                     const unsigned short* __restrict__ Sprev,
                                                     const float* __restrict__ brp,
                                                     const int* __restrict__ deg,
                                                     const int* __restrict__ esrc,
                                                     const unsigned short* __restrict__ Wt,
                                                     void* __restrict__ Tout,
                                                     unsigned short* __restrict__ Sout) {
    constexpr int NB  = 2 * DO;          // 256 or 128
    constexpr int NBW = NB / 4;          // cols per wave
    constexpr int CF  = NBW / 16;        // col frags per wave (4 or 2)

    __shared__ unsigned short AsMem[32 * 128];   // 8 KB
    __shared__ unsigned short BsMem[NB * 64];    // 32 KB (NB=256) / 16 KB
    uint4* As4 = (uint4*)AsMem;
    uint4* Bs4 = (uint4*)BsMem;

    const int tid  = threadIdx.x;
    const int m0   = blockIdx.x * 32;
    const int wave = tid >> 6;
    const int lane = tid & 63;
    const int qm   = lane & 15;
    const int hi   = lane >> 4;
    const int wcb  = wave * NBW;

    // ---- A: aggregate prologue / fp32 stage (gathers issued first)
    if (AGG) {
        const int noderow = tid >> 3;    // 0..31
        const int lane8   = tid & 7;     // dims lane8*16..+15
        const int n       = m0 + noderow;
        if (n < N_NODES) {
            int cnt = deg[n];
            if (cnt > ROW_CAP) cnt = ROW_CAP;
            const int* erow = esrc + (size_t)n * ROW_CAP;
            const uint4* T8 = (const uint4*)Ain;  // fp8 row = 8 uint4
            v2f acc[8];
#pragma unroll
            for (int i = 0; i < 8; i++) acc[i] = (v2f)(0.0f);
            for (int o = 0; o < cnt; o += 8) {
                int4 i0 = *(const int4*)(erow + o);
                int4 i1 = *(const int4*)(erow + o + 4);
                i0.x = (o + 0 < cnt) ? i0.x : N_NODES;
                i0.y = (o + 1 < cnt) ? i0.y : N_NODES;
                i0.z = (o + 2 < cnt) ? i0.z : N_NODES;
                i0.w = (o + 3 < cnt) ? i0.w : N_NODES;
                i1.x = (o + 4 < cnt) ? i1.x : N_NODES;
                i1.y = (o + 5 < cnt) ? i1.y : N_NODES;
                i1.z = (o + 6 < cnt) ? i1.z : N_NODES;
                i1.w = (o + 7 < cnt) ? i1.w : N_NODES;
                uint4 q0 = T8[(size_t)i0.x * 8 + lane8];
                uint4 q1 = T8[(size_t)i0.y * 8 + lane8];
                uint4 q2 = T8[(size_t)i0.z * 8 + lane8];
                uint4 q3 = T8[(size_t)i0.w * 8 + lane8];
                uint4 q4 = T8[(size_t)i1.x * 8 + lane8];
                uint4 q5 = T8[(size_t)i1.y * 8 + lane8];
                uint4 q6 = T8[(size_t)i1.z * 8 + lane8];
                uint4 q7 = T8[(size_t)i1.w * 8 + lane8];
                addp16(acc, q0); addp16(acc, q1); addp16(acc, q2); addp16(acc, q3);
                addp16(acc, q4); addp16(acc, q5); addp16(acc, q6); addp16(acc, q7);
            }
            // + S (bf16 exact) + bias, relu, pack 16 dims -> 2 uint4
            uint4 sv0 = ((const uint4*)Sprev)[(size_t)n * 16 + lane8 * 2];
            uint4 sv1 = ((const uint4*)Sprev)[(size_t)n * 16 + lane8 * 2 + 1];
            addp(acc, sv0); addp(acc + 4, sv1);
            float vv[16];
#pragma unroll
            for (int j = 0; j < 16; j++) {
                float bj = brp[lane8 * 16 + j];
                vv[j] = fmaxf(((j & 1) ? acc[j >> 1].y : acc[j >> 1].x) + bj, 0.f);
            }
#pragma unroll
            for (int h = 0; h < 2; h++) {
                uint4 o;
                o.x = (unsigned)f2b(vv[h * 8 + 0]) | ((unsigned)f2b(vv[h * 8 + 1]) << 16);
                o.y = (unsigned)f2b(vv[h * 8 + 2]) | ((unsigned)f2b(vv[h * 8 + 3]) << 16);
                o.z = (unsigned)f2b(vv[h * 8 + 4]) | ((unsigned)f2b(vv[h * 8 + 5]) << 16);
                o.w = (unsigned)f2b(vv[h * 8 + 6]) | ((unsigned)f2b(vv[h * 8 + 7]) << 16);
                As4[noderow * 16 + ((lane8 * 2 + h) ^ (noderow & 7))] = o;
            }
        } else {
            uint4 z = make_uint4(0, 0, 0, 0);
#pragma unroll
            for (int h = 0; h < 2; h++)
                As4[noderow * 16 + ((lane8 * 2 + h) ^ (noderow & 7))] = z;
        }
    } else if (F32) {
        const float4* Xg = (const float4*)Ain;       // row pitch 32 float4
#pragma unroll
        for (int i = 0; i < 2; i++) {
            int idx = i * 256 + tid;                 // uint4 slot 0..511
            int row = idx >> 4, c = idx & 15;        // c = 8-dim chunk
            int gr = m0 + row;
            if (gr > N_NODES - 1) gr = N_NODES - 1;  // pad clamp
            float4 a = Xg[(size_t)gr * 32 + c * 2];
            float4 b = Xg[(size_t)gr * 32 + c * 2 + 1];
            uint4 o;
            o.x = (unsigned)f2b(a.x) | ((unsigned)f2b(a.y) << 16);
            o.y = (unsigned)f2b(a.z) | ((unsigned)f2b(a.w) << 16);
            o.z = (unsigned)f2b(b.x) | ((unsigned)f2b(b.y) << 16);
            o.w = (unsigned)f2b(b.z) | ((unsigned)f2b(b.w) << 16);
            As4[row * 16 + (c ^ (row & 7))] = o;
        }
    } else {
        const unsigned short* Ab = (const unsigned short*)Ain;
#pragma unroll
        for (int i = 0; i < 2; i++) {
            int idx = i * 256 + tid;
            int row = idx >> 4, c = idx & 15;
            int gr = m0 + row;
            if (gr > N_NODES - 1) gr = N_NODES - 1;
            As4[row * 16 + (c ^ (row & 7))] =
                *(const uint4*)(Ab + (size_t)gr * 128 + c * 8);
        }
    }

    // ---- stage B half 0 (after gather issue)
#pragma unroll
    for (int i = 0; i < NB * 8 / 256; i++) {
        int idx = i * 256 + tid;
        int row = idx >> 3, c8 = idx & 7;
        Bs4[row * 8 + (c8 ^ (row & 7))] =
            *(const uint4*)(Wt + (size_t)row * 128 + c8 * 8);
    }
    __syncthreads();

    // ---- MFMA: K=128 in 2 halves; Bs restaged between halves
    v4f acc[2][CF];
#pragma unroll
    for (int i = 0; i < 2; i++)
#pragma unroll
        for (int j = 0; j < CF; j++) acc[i][j] = (v4f)(0.0f);

#pragma unroll
    for (int half = 0; half < 2; half++) {
        if (half == 1) {
            __syncthreads();
#pragma unroll
            for (int i = 0; i < NB * 8 / 256; i++) {
                int idx = i * 256 + tid;
                int row = idx >> 3, c8 = idx & 7;
                Bs4[row * 8 + (c8 ^ (row & 7))] =
                    *(const uint4*)(Wt + (size_t)row * 128 + 64 + c8 * 8);
            }
            __syncthreads();
        }
#pragma unroll
        for (int ks = 0; ks < 2; ks++) {
            short8 af[2], bf[CF];
#pragma unroll
            for (int mi = 0; mi < 2; mi++) {
                const int r  = mi * 16 + qm;
                const int ca = half * 8 + ks * 4 + hi;
                af[mi] = *(const short8*)&As4[r * 16 + (ca ^ (r & 7))];
            }
#pragma unroll
            for (int ni = 0; ni < CF; ni++) {
                const int rb = wcb + ni * 16 + qm;
                const int cb = ks * 4 + hi;
                bf[ni] = *(const short8*)&Bs4[rb * 8 + (cb ^ (rb & 7))];
            }
#pragma unroll
            for (int mi = 0; mi < 2; mi++)
#pragma unroll
                for (int ni = 0; ni < CF; ni++)
                    acc[mi][ni] = __builtin_amdgcn_mfma_f32_16x16x32_bf16(af[mi], bf[ni], acc[mi][ni], 0, 0, 0);
        }
    }
    __syncthreads();

    // ---- epilogue: acc -> Es (=Bs region) bf16 [32][NB], R15 sw-XOR
    unsigned short* Es = BsMem;
#pragma unroll
    for (int mi = 0; mi < 2; mi++) {
        const int rowBase = mi * 16 + (hi << 2);
#pragma unroll
        for (int r = 0; r < 4; r++) {
            const int row = rowBase + r;
            const int sw  = ((row >> 2) & 3) << 4;
#pragma unroll
            for (int ni = 0; ni < CF; ni++) {
                const int c = wcb + ni * 16 + qm;
                Es[row * NB + (c ^ sw)] = f2b(acc[mi][ni][r]);
            }
        }
    }
    __syncthreads();

    if (DO == 128) {
        // T fp8: 32 rows x 8 chunks(16 dims) = 256 chunks, 1/thread
        unsigned char* T8o = (unsigned char*)Tout;
        {
            const int chunk = tid;
            const int row   = chunk >> 3;
            const int c0    = (chunk & 7) * 16;
            const int sw    = ((row >> 2) & 3) << 4;
            const int node  = m0 + row;
            if (node <= N_NODES) {
                uint4 v = make_uint4(0, 0, 0, 0);
                if (node < N_NODES) {
                    const unsigned short* p = Es + row * 256 + (c0 ^ sw);
                    uint4 ha = *(const uint4*)p;
                    uint4 hb = *(const uint4*)(p + 8);
#define LOF(d) __uint_as_float((d) << 16)
#define HIF(d) __uint_as_float((d) & 0xffff0000u)
                    v.x = pack4_fp8(LOF(ha.x), HIF(ha.x), LOF(ha.y), HIF(ha.y));
                    v.y = pack4_fp8(LOF(ha.z), HIF(ha.z), LOF(ha.w), HIF(ha.w));
                    v.z = pack4_fp8(LOF(hb.x), HIF(hb.x), LOF(hb.y), HIF(hb.y));
                    v.w = pack4_fp8(LOF(hb.z), HIF(hb.z), LOF(hb.w), HIF(hb.w));
#undef LOF
#undef HIF
                }
                *(uint4*)(T8o + (size_t)node * 128 + c0) = v;
            }
        }
        // S bf16: cols 128..255 = 512 16B chunks, 2/thread
#pragma unroll
        for (int i = 0; i < 2; i++) {
            const int chunk = i * 256 + tid;
            const int row   = chunk >> 4;
            const int c0    = 128 + (chunk & 15) * 8;
            const int sw    = ((row >> 2) & 3) << 4;
            const int node  = m0 + row;
            if (node <= N_NODES) {
                uint4 v = make_uint4(0, 0, 0, 0);
                if (node < N_NODES)
                    v = *(const uint4*)(Es + row * 256 + (c0 ^ sw));
                *(uint4*)(Sout + (size_t)node * 128 + (c0 - 128)) = v;
            }
        }
    } else {
        // DO=64: [32][128] = 512 chunks, 2/thread; T cols 0..63, S 64..127
        unsigned short* Tb = (unsigned short*)Tout;
#pragma unroll
        for (int i = 0; i < 2; i++) {
            const int chunk = i * 256 + tid;
            const int row   = chunk >> 4;
            const int c0    = (chunk & 15) * 8;
            const int sw    = ((row >> 2) & 3) << 4;
            const int node  = m0 + row;
            if (node <= N_NODES) {
                uint4 v = make_uint4(0, 0, 0, 0);
                if (node < N_NODES)
                    v = *(const uint4*)(Es + row * 128 + (c0 ^ sw));
                if (c0 < 64) *(uint4*)(Tb + (size_t)node * 64 + c0) = v;
                else         *(uint4*)(Sout + (size_t)node * 64 + (c0 - 64)) = v;
            }
        }
    }
}

// ---------------------------------------------------------------- final aggregate
// Layer 3 agg + log_softmax: 16 lanes/node = 2 edge groups of 8, merged via
// shfl_xor(8); bf16 T row = 8 uint4.
__global__ __launch_bounds__(256) void agg_last_kernel(const unsigned short* __restrict__ T,
                                                       const unsigned short* __restrict__ S,
                                                       const float* __restrict__ br,
                                                       const int* __restrict__ deg,
                                                       const int* __restrict__ esrc,
                                                       float* __restrict__ Fout) {
    const int lane16 = threadIdx.x & 15;
    const int g      = lane16 >> 3;
    const int lane   = lane16 & 7;
    const int n      = blockIdx.x * 16 + (threadIdx.x >> 4);

    int cnt = deg[n];
    if (cnt > ROW_CAP) cnt = ROW_CAP;
    const int* erow = esrc + (size_t)n * ROW_CAP;
    const uint4* T4 = (const uint4*)T;

    v2f acc[4];
    acc[0] = (v2f)(0.0f); acc[1] = (v2f)(0.0f);
    acc[2] = (v2f)(0.0f); acc[3] = (v2f)(0.0f);

    for (int o = g * 8; o < cnt; o += 16) {
        int4 i0 = *(const int4*)(erow + o);
        int4 i1 = *(const int4*)(erow + o + 4);
        i0.x = (o + 0 < cnt) ? i0.x : N_NODES;
        i0.y = (o + 1 < cnt) ? i0.y : N_NODES;
        i0.z = (o + 2 < cnt) ? i0.z : N_NODES;
        i0.w = (o + 3 < cnt) ? i0.w : N_NODES;
        i1.x = (o + 4 < cnt) ? i1.x : N_NODES;
        i1.y = (o + 5 < cnt) ? i1.y : N_NODES;
        i1.z = (o + 6 < cnt) ? i1.z : N_NODES;
        i1.w = (o + 7 < cnt) ? i1.w : N_NODES;
        uint4 q0 = T4[(size_t)i0.x * 8 + lane];
        uint4 q1 = T4[(size_t)i0.y * 8 + lane];
        uint4 q2 = T4[(size_t)i0.z * 8 + lane];
        uint4 q3 = T4[(size_t)i0.w * 8 + lane];
        uint4 q4 = T4[(size_t)i1.x * 8 + lane];
        uint4 q5 = T4[(size_t)i1.y * 8 + lane];
        uint4 q6 = T4[(size_t)i1.z * 8 + lane];
        uint4 q7 = T4[(size_t)i1.w * 8 + lane];
        addp(acc, q0); addp(acc, q1); addp(acc, q2); addp(acc, q3);
        addp(acc, q4); addp(acc, q5); addp(acc, q6); addp(acc, q7);
    }
#pragma unroll
    for (int i = 0; i < 4; i++) {
        acc[i].x += __shfl_xor(acc[i].x, 8);
        acc[i].y += __shfl_xor(acc[i].y, 8);
    }

    uint4 sv = ((const uint4*)S)[(size_t)n * 8 + lane];
    addp(acc, sv);
    const float4 b0 = ((const float4*)br)[lane * 2];
    const float4 b1 = ((const float4*)br)[lane * 2 + 1];

    float v[8];
    v[0] = fmaxf(acc[0].x + b0.x, 0.f); v[1] = fmaxf(acc[0].y + b0.y, 0.f);
    v[2] = fmaxf(acc[1].x + b0.z, 0.f); v[3] = fmaxf(acc[1].y + b0.w, 0.f);
    v[4] = fmaxf(acc[2].x + b1.x, 0.f); v[5] = fmaxf(acc[2].y + b1.y, 0.f);
    v[6] = fmaxf(acc[3].x + b1.z, 0.f); v[7] = fmaxf(acc[3].y + b1.w, 0.f);

    float m = v[0];
#pragma unroll
    for (int i = 1; i < 8; i++) m = fmaxf(m, v[i]);
#pragma unroll
    for (int off = 4; off; off >>= 1) m = fmaxf(m, __shfl_xor(m, off));
    float es = 0.f;
#pragma unroll
    for (int i = 0; i < 8; i++) es += expf(v[i] - m);
#pragma unroll
    for (int off = 4; off; off >>= 1) es += __shfl_xor(es, off);
    float lse = m + logf(es);
    if (g == 0) {
        float4 o0 = make_float4(v[0] - lse, v[1] - lse, v[2] - lse, v[3] - lse);
        float4 o1 = make_float4(v[4] - lse, v[5] - lse, v[6] - lse, v[7] - lse);
        ((float4*)Fout)[(size_t)n * 16 + lane * 2]     = o0;
        ((float4*)Fout)[(size_t)n * 16 + lane * 2 + 1] = o1;
    }
}

// ---------------------------------------------------------------- launch

extern "C" void kernel_launch(void* const* d_in, const int* in_sizes, int n_in,
                              void* d_out, int out_size, void* d_ws, size_t ws_size,
                              hipStream_t stream) {
    const float* x    = (const float*)d_in[0];
    const int*   eidx = (const int*)d_in[1];   // [2, E] int32
    const float* Wr0  = (const float*)d_in[2];
    const float* br0  = (const float*)d_in[3];
    const float* Ws0  = (const float*)d_in[4];
    const float* Wr1  = (const float*)d_in[5];
    const float* br1  = (const float*)d_in[6];
    const float* Ws1  = (const float*)d_in[7];
    const float* Wr2  = (const float*)d_in[8];
    const float* br2  = (const float*)d_in[9];
    const float* Ws2  = (const float*)d_in[10];
    float* out = (float*)d_out;

    const int* src = eidx;
    const int* dst = eidx + N_EDGES;

    auto align = [](size_t v) { return (v + 255) & ~(size_t)255; };
    char* w = (char*)d_ws;
    int* deg  = (int*)w;  w += align(sizeof(int) * DEG_CAP);
    int* esrc = (int*)w;  w += align(sizeof(int) * (size_t)N_NODES * ROW_CAP);
    unsigned short* Wt0 = (unsigned short*)w;  w += align(2ull * 256 * 128);
    unsigned short* Wt1 = (unsigned short*)w;  w += align(2ull * 256 * 128);
    unsigned short* Wt2 = (unsigned short*)w;  w += align(2ull * 128 * 128);
    void* T_a = (void*)w;                      w += align(2ull * PAD_NODES * 64);  // fp8 128 / bf16 64
    void* T_b = (void*)w;                      w += align(2ull * PAD_NODES * 64);
    unsigned short* S_a = (unsigned short*)w;  w += align(2ull * PAD_NODES * 128);
    unsigned short* S_b = (unsigned short*)w;  w += align(2ull * PAD_NODES * 128);
    (void)ws_size; (void)n_in; (void)in_sizes; (void)out_size;

    // ---- deg zero (async memset) + fused prep/place
    hipMemsetAsync(deg, 0, sizeof(int) * DEG_CAP, stream);
    prep_place_kernel<<<2820, 256, 0, stream>>>(
        src, dst, deg, esrc, Wr0, Ws0, Wr1, Ws1, Wr2, Ws2, Wt0, Wt1, Wt2);

    // ---- layer 1: mm only (fp32 x -> T_a fp8, S_a)
    mmf_kernel<128, false, true><<<PAD_NODES / 32, 256, 0, stream>>>(
        x, nullptr, nullptr, nullptr, nullptr, Wt0, T_a, S_a);

    // ---- layer 2: agg(L1) prologue + mm (T_a,S_a -> T_b fp8, S_b)
    mmf_kernel<128, true, false><<<PAD_NODES / 32, 256, 0, stream>>>(
        T_a, S_a, br0, deg, esrc, Wt1, T_b, S_b);

    // ---- layer 3: agg(L2) prologue + mm (T_b,S_b -> T_a bf16[64], S_a[64])
    mmf_kernel<64, true, false><<<PAD_NODES / 32, 256, 0, stream>>>(
        T_b, S_b, br1, deg, esrc, Wt2, T_a, S_a);

    // ---- final aggregate + log_softmax
    agg_last_kernel<<<N_NODES / 16, 256, 0, stream>>>(
        (const unsigned short*)T_a, S_a, br2, deg, esrc, out);
}

// Round 12
// 183.699 us; speedup vs baseline: 1.1930x; 1.0073x over previous
//
#include <hip/hip_runtime.h>
#include <hip/hip_bf16.h>

// GraphConv x3 + ReLU + log_softmax on MI355X — bf16/MFMA pipeline.
// LEDGER (keep):
// R11/R16/R12: place fusion/spreading dead ends — place ~10us.
// R13/R14: L2-residency for gather impossible; NT sub-line stores bad.
// R15 (WIN): swizzled-LDS transpose epilogue -> 16B stores.
// R17/R18/R19 (currency model): gather cost ~ per-lane VMEM REQUEST count.
//      R17 fp8@16req/edge=no gain; R18 fp8@8req=gain; R19 2xTLP=+4 (MSHR
//      cap). 128B row @16B loads => 8 req/edge is the floor for DO=128.
// R20 (WIN): agg fused as next mm's prologue (H never hits HBM).
// R21 (WIN 193->185): x staged fp32 direct; prep+place merged LDS-free;
//      32-row tile grid 1252 @(256,3) = 1.63 rounds (cross-round overlap).
// R22: (a) T3 (layer-3 aggregated term) in fp8: 64B row -> 4 req/edge in
//      agg_last (4 lanes/node x 16 dims, 4 edge groups, shfl_xor(4,8)
//      merge) — the one gather not at its request floor. absmax risk
//      pre-committed: revert (a) alone if correctness fails.
//      (b) v_cvt_pk_f32_fp8 unpack (2 fp8/instr): gather VALU 24->16 per
//      16B load in all fp8 paths.

#define N_NODES 40000
#define N_EDGES 640000
#define PAD_NODES 40064        // 1252 * 32
#define DEG_CAP   40960
#define ROW_CAP   64           // esrc slots per node

typedef float v4f __attribute__((ext_vector_type(4)));
typedef float v2f __attribute__((ext_vector_type(2)));
typedef short short8 __attribute__((ext_vector_type(8)));

__device__ inline unsigned short f2b(float f) {  // RNE fp32->bf16
    unsigned u = __float_as_uint(f);
    return (unsigned short)((u + 0x7fffu + ((u >> 16) & 1u)) >> 16);
}

// bf16 -> fp8 e4m3 (OCP), RNE, FTZ below 2^-6, clamp 448 (fallback path).
__device__ inline unsigned b2f8(unsigned short us) {
    unsigned s  = ((unsigned)us >> 8) & 0x80u;
    unsigned mag = us & 0x7fffu;
    unsigned e8 = mag >> 7, m7 = mag & 0x7fu;
    unsigned out;
    if (e8 < 121u) out = 0u;
    else if (e8 > 135u) out = 0x7eu;
    else {
        unsigned e4 = e8 - 120u;
        unsigned r  = (m7 + 7u + ((m7 >> 4) & 1u)) >> 4;
        if (r == 8u) { r = 0u; e4++; }
        out = (e4 > 15u || (e4 == 15u && r > 6u)) ? 0x7eu : ((e4 << 3) | r);
    }
    return s | out;
}

__device__ inline unsigned pack4_fp8(float f0, float f1, float f2, float f3) {
#if __has_builtin(__builtin_amdgcn_cvt_pk_fp8_f32)
    int w = __builtin_amdgcn_cvt_pk_fp8_f32(f0, f1, 0, false);
    w = __builtin_amdgcn_cvt_pk_fp8_f32(f2, f3, w, true);
    return (unsigned)w;
#else
    return b2f8(f2b(f0)) | (b2f8(f2b(f1)) << 8) |
           (b2f8(f2b(f2)) << 16) | (b2f8(f2b(f3)) << 24);
#endif
}

#if __has_builtin(__builtin_amdgcn_cvt_f32_fp8)
#define F8TOF(w, sel) __builtin_amdgcn_cvt_f32_fp8((int)(w), (sel))
#else
__device__ inline float f8tof_(unsigned b) {
    unsigned e = (b >> 3) & 15u;
    unsigned bits = ((b & 0x80u) << 24) |
                    (e ? (((e + 120u) << 23) | ((b & 7u) << 20)) : 0u);
    return __uint_as_float(bits);
}
#define F8TOF(w, sel) f8tof_(((unsigned)(w) >> ((sel) * 8)) & 0xffu)
#endif

__device__ inline void addp(v2f* a, uint4 q) {       // 8 bf16
    v2f t0 = { __uint_as_float(q.x << 16), __uint_as_float(q.x & 0xffff0000u) };
    v2f t1 = { __uint_as_float(q.y << 16), __uint_as_float(q.y & 0xffff0000u) };
    v2f t2 = { __uint_as_float(q.z << 16), __uint_as_float(q.z & 0xffff0000u) };
    v2f t3 = { __uint_as_float(q.w << 16), __uint_as_float(q.w & 0xffff0000u) };
    a[0] += t0; a[1] += t1; a[2] += t2; a[3] += t3;
}
// 4 fp8 -> 2 v2f; packed-cvt path (R22b) does 2 fp8 per instruction.
__device__ inline void addp8w(v2f* a, unsigned w) {
#if __has_builtin(__builtin_amdgcn_cvt_pk_f32_fp8)
    typedef float f2v __attribute__((ext_vector_type(2)));
    f2v lo = __builtin_amdgcn_cvt_pk_f32_fp8((int)w, false);
    f2v hi = __builtin_amdgcn_cvt_pk_f32_fp8((int)w, true);
    a[0].x += lo.x; a[0].y += lo.y;
    a[1].x += hi.x; a[1].y += hi.y;
#else
    v2f t0 = { F8TOF(w, 0), F8TOF(w, 1) };
    v2f t1 = { F8TOF(w, 2), F8TOF(w, 3) };
    a[0] += t0; a[1] += t1;
#endif
}
__device__ inline void addp16(v2f* a, uint4 q) {     // 16 fp8 -> a[0..7]
    addp8w(a + 0, q.x); addp8w(a + 2, q.y);
    addp8w(a + 4, q.z); addp8w(a + 6, q.w);
}

// ---------------------------------------------------------------- prep+place
// LDS-free fused kernel: blocks [0,2500) place edges (full occupancy);
// blocks [2500,2820) do W casts. deg zeroed by hipMemsetAsync.
__global__ __launch_bounds__(256) void prep_place_kernel(const int* __restrict__ src,
                                                         const int* __restrict__ dst,
                                                         int* __restrict__ deg,
                                                         int* __restrict__ esrc,
                                                         const float* __restrict__ Wr0, const float* __restrict__ Ws0,
                                                         const float* __restrict__ Wr1, const float* __restrict__ Ws1,
                                                         const float* __restrict__ Wr2, const float* __restrict__ Ws2,
                                                         unsigned short* __restrict__ Wt0,
                                                         unsigned short* __restrict__ Wt1,
                                                         unsigned short* __restrict__ Wt2) {
    const int bid = blockIdx.x;
    if (bid < 2500) {
        int e = bid * 256 + threadIdx.x;
        if (e < N_EDGES) {
            int d = dst[e];
            int r = atomicAdd(&deg[d], 1);
            if (r < ROW_CAP) esrc[(size_t)d * ROW_CAP + r] = src[e];
        }
    } else {
        int t = (bid - 2500) * 256 + threadIdx.x;   // 0..81919
        if (t < 32768) {
            int n = t >> 7, k = t & 127;
            const float* W = (n < 128) ? Wr0 : Ws0;
            Wt0[t] = f2b(W[k * 128 + (n & 127)]);
        } else if (t < 65536) {
            int u = t - 32768;
            int n = u >> 7, k = u & 127;
            const float* W = (n < 128) ? Wr1 : Ws1;
            Wt1[u] = f2b(W[k * 128 + (n & 127)]);
        } else if (t < 81920) {
            int u = t - 65536;
            int n = u >> 7, k = u & 127;
            const float* W = (n < 64) ? Wr2 : Ws2;
            Wt2[u] = f2b(W[k * 64 + (n & 63)]);
        }
    }
}

// ---------------------------------------------------------------- fused mm
// Block owns 32 rows x full NB=2*DO cols; grid 1252; LDS = As 8KB +
// Bs 32/16KB; (256,3) -> 1.63 rounds. AGG: 8 lanes/node x 16 dims,
// 1 uint4/edge/lane fp8 gather (8 req/edge = floor). F32: stage fp32 x.
// Epilogue: swizzled Es -> 16B stores; DO=128: T fp8 + S bf16;
// DO=64 (layer 3): T fp8 (R22a, 64B row) + S bf16.
// node==N_NODES row forced zeros (dummy row for pad-slot gathers).
template <int DO, bool AGG, bool F32>
__global__ __launch_bounds__(256, 3) void mmf_kernel(const void* __restrict__ Ain,
                                                     const unsigned short* __restrict__ Sprev,
                                                     const float* __restrict__ brp,
                                                     const int* __restrict__ deg,
                                                     const int* __restrict__ esrc,
                                                     const unsigned short* __restrict__ Wt,
                                                     void* __restrict__ Tout,
                                                     unsigned short* __restrict__ Sout) {
    constexpr int NB  = 2 * DO;          // 256 or 128
    constexpr int NBW = NB / 4;          // cols per wave
    constexpr int CF  = NBW / 16;        // col frags per wave (4 or 2)

    __shared__ unsigned short AsMem[32 * 128];   // 8 KB
    __shared__ unsigned short BsMem[NB * 64];    // 32 KB (NB=256) / 16 KB
    uint4* As4 = (uint4*)AsMem;
    uint4* Bs4 = (uint4*)BsMem;

    const int tid  = threadIdx.x;
    const int m0   = blockIdx.x * 32;
    const int wave = tid >> 6;
    const int lane = tid & 63;
    const int qm   = lane & 15;
    const int hi   = lane >> 4;
    const int wcb  = wave * NBW;

    // ---- A: aggregate prologue / fp32 stage (gathers issued first)
    if (AGG) {
        const int noderow = tid >> 3;    // 0..31
        const int lane8   = tid & 7;     // dims lane8*16..+15
        const int n       = m0 + noderow;
        if (n < N_NODES) {
            int cnt = deg[n];
            if (cnt > ROW_CAP) cnt = ROW_CAP;
            const int* erow = esrc + (size_t)n * ROW_CAP;
            const uint4* T8 = (const uint4*)Ain;  // fp8 row = 8 uint4
            v2f acc[8];
#pragma unroll
            for (int i = 0; i < 8; i++) acc[i] = (v2f)(0.0f);
            for (int o = 0; o < cnt; o += 8) {
                int4 i0 = *(const int4*)(erow + o);
                int4 i1 = *(const int4*)(erow + o + 4);
                i0.x = (o + 0 < cnt) ? i0.x : N_NODES;
                i0.y = (o + 1 < cnt) ? i0.y : N_NODES;
                i0.z = (o + 2 < cnt) ? i0.z : N_NODES;
                i0.w = (o + 3 < cnt) ? i0.w : N_NODES;
                i1.x = (o + 4 < cnt) ? i1.x : N_NODES;
                i1.y = (o + 5 < cnt) ? i1.y : N_NODES;
                i1.z = (o + 6 < cnt) ? i1.z : N_NODES;
                i1.w = (o + 7 < cnt) ? i1.w : N_NODES;
                uint4 q0 = T8[(size_t)i0.x * 8 + lane8];
                uint4 q1 = T8[(size_t)i0.y * 8 + lane8];
                uint4 q2 = T8[(size_t)i0.z * 8 + lane8];
                uint4 q3 = T8[(size_t)i0.w * 8 + lane8];
                uint4 q4 = T8[(size_t)i1.x * 8 + lane8];
                uint4 q5 = T8[(size_t)i1.y * 8 + lane8];
                uint4 q6 = T8[(size_t)i1.z * 8 + lane8];
                uint4 q7 = T8[(size_t)i1.w * 8 + lane8];
                addp16(acc, q0); addp16(acc, q1); addp16(acc, q2); addp16(acc, q3);
                addp16(acc, q4); addp16(acc, q5); addp16(acc, q6); addp16(acc, q7);
            }
            // + S (bf16 exact) + bias, relu, pack 16 dims -> 2 uint4
            uint4 sv0 = ((const uint4*)Sprev)[(size_t)n * 16 + lane8 * 2];
            uint4 sv1 = ((const uint4*)Sprev)[(size_t)n * 16 + lane8 * 2 + 1];
            addp(acc, sv0); addp(acc + 4, sv1);
            float vv[16];
#pragma unroll
            for (int j = 0; j < 16; j++) {
                float bj = brp[lane8 * 16 + j];
                vv[j] = fmaxf(((j & 1) ? acc[j >> 1].y : acc[j >> 1].x) + bj, 0.f);
            }
#pragma unroll
            for (int h = 0; h < 2; h++) {
                uint4 o;
                o.x = (unsigned)f2b(vv[h * 8 + 0]) | ((unsigned)f2b(vv[h * 8 + 1]) << 16);
                o.y = (unsigned)f2b(vv[h * 8 + 2]) | ((unsigned)f2b(vv[h * 8 + 3]) << 16);
                o.z = (unsigned)f2b(vv[h * 8 + 4]) | ((unsigned)f2b(vv[h * 8 + 5]) << 16);
                o.w = (unsigned)f2b(vv[h * 8 + 6]) | ((unsigned)f2b(vv[h * 8 + 7]) << 16);
                As4[noderow * 16 + ((lane8 * 2 + h) ^ (noderow & 7))] = o;
            }
        } else {
            uint4 z = make_uint4(0, 0, 0, 0);
#pragma unroll
            for (int h = 0; h < 2; h++)
                As4[noderow * 16 + ((lane8 * 2 + h) ^ (noderow & 7))] = z;
        }
    } else if (F32) {
        const float4* Xg = (const float4*)Ain;       // row pitch 32 float4
#pragma unroll
        for (int i = 0; i < 2; i++) {
            int idx = i * 256 + tid;                 // uint4 slot 0..511
            int row = idx >> 4, c = idx & 15;        // c = 8-dim chunk
            int gr = m0 + row;
            if (gr > N_NODES - 1) gr = N_NODES - 1;  // pad clamp
            float4 a = Xg[(size_t)gr * 32 + c * 2];
            float4 b = Xg[(size_t)gr * 32 + c * 2 + 1];
            uint4 o;
            o.x = (unsigned)f2b(a.x) | ((unsigned)f2b(a.y) << 16);
            o.y = (unsigned)f2b(a.z) | ((unsigned)f2b(a.w) << 16);
            o.z = (unsigned)f2b(b.x) | ((unsigned)f2b(b.y) << 16);
            o.w = (unsigned)f2b(b.z) | ((unsigned)f2b(b.w) << 16);
            As4[row * 16 + (c ^ (row & 7))] = o;
        }
    } else {
        const unsigned short* Ab = (const unsigned short*)Ain;
#pragma unroll
        for (int i = 0; i < 2; i++) {
            int idx = i * 256 + tid;
            int row = idx >> 4, c = idx & 15;
            int gr = m0 + row;
            if (gr > N_NODES - 1) gr = N_NODES - 1;
            As4[row * 16 + (c ^ (row & 7))] =
                *(const uint4*)(Ab + (size_t)gr * 128 + c * 8);
        }
    }

    // ---- stage B half 0 (after gather issue)
#pragma unroll
    for (int i = 0; i < NB * 8 / 256; i++) {
        int idx = i * 256 + tid;
        int row = idx >> 3, c8 = idx & 7;
        Bs4[row * 8 + (c8 ^ (row & 7))] =
            *(const uint4*)(Wt + (size_t)row * 128 + c8 * 8);
    }
    __syncthreads();

    // ---- MFMA: K=128 in 2 halves; Bs restaged between halves
    v4f acc[2][CF];
#pragma unroll
    for (int i = 0; i < 2; i++)
#pragma unroll
        for (int j = 0; j < CF; j++) acc[i][j] = (v4f)(0.0f);

#pragma unroll
    for (int half = 0; half < 2; half++) {
        if (half == 1) {
            __syncthreads();
#pragma unroll
            for (int i = 0; i < NB * 8 / 256; i++) {
                int idx = i * 256 + tid;
                int row = idx >> 3, c8 = idx & 7;
                Bs4[row * 8 + (c8 ^ (row & 7))] =
                    *(const uint4*)(Wt + (size_t)row * 128 + 64 + c8 * 8);
            }
            __syncthreads();
        }
#pragma unroll
        for (int ks = 0; ks < 2; ks++) {
            short8 af[2], bf[CF];
#pragma unroll
            for (int mi = 0; mi < 2; mi++) {
                const int r  = mi * 16 + qm;
                const int ca = half * 8 + ks * 4 + hi;
                af[mi] = *(const short8*)&As4[r * 16 + (ca ^ (r & 7))];
            }
#pragma unroll
            for (int ni = 0; ni < CF; ni++) {
                const int rb = wcb + ni * 16 + qm;
                const int cb = ks * 4 + hi;
                bf[ni] = *(const short8*)&Bs4[rb * 8 + (cb ^ (rb & 7))];
            }
#pragma unroll
            for (int mi = 0; mi < 2; mi++)
#pragma unroll
                for (int ni = 0; ni < CF; ni++)
                    acc[mi][ni] = __builtin_amdgcn_mfma_f32_16x16x32_bf16(af[mi], bf[ni], acc[mi][ni], 0, 0, 0);
        }
    }
    __syncthreads();

    // ---- epilogue: acc -> Es (=Bs region) bf16 [32][NB], R15 sw-XOR
    unsigned short* Es = BsMem;
#pragma unroll
    for (int mi = 0; mi < 2; mi++) {
        const int rowBase = mi * 16 + (hi << 2);
#pragma unroll
        for (int r = 0; r < 4; r++) {
            const int row = rowBase + r;
            const int sw  = ((row >> 2) & 3) << 4;
#pragma unroll
            for (int ni = 0; ni < CF; ni++) {
                const int c = wcb + ni * 16 + qm;
                Es[row * NB + (c ^ sw)] = f2b(acc[mi][ni][r]);
            }
        }
    }
    __syncthreads();

#define LOF(d) __uint_as_float((d) << 16)
#define HIF(d) __uint_as_float((d) & 0xffff0000u)
    if (DO == 128) {
        // T fp8: 32 rows x 8 chunks(16 dims) = 256 chunks, 1/thread
        unsigned char* T8o = (unsigned char*)Tout;
        {
            const int chunk = tid;
            const int row   = chunk >> 3;
            const int c0    = (chunk & 7) * 16;
            const int sw    = ((row >> 2) & 3) << 4;
            const int node  = m0 + row;
            if (node <= N_NODES) {
                uint4 v = make_uint4(0, 0, 0, 0);
                if (node < N_NODES) {
                    const unsigned short* p = Es + row * 256 + (c0 ^ sw);
                    uint4 ha = *(const uint4*)p;
                    uint4 hb = *(const uint4*)(p + 8);
                    v.x = pack4_fp8(LOF(ha.x), HIF(ha.x), LOF(ha.y), HIF(ha.y));
                    v.y = pack4_fp8(LOF(ha.z), HIF(ha.z), LOF(ha.w), HIF(ha.w));
                    v.z = pack4_fp8(LOF(hb.x), HIF(hb.x), LOF(hb.y), HIF(hb.y));
                    v.w = pack4_fp8(LOF(hb.z), HIF(hb.z), LOF(hb.w), HIF(hb.w));
                }
                *(uint4*)(T8o + (size_t)node * 128 + c0) = v;
            }
        }
        // S bf16: cols 128..255 = 512 16B chunks, 2/thread
#pragma unroll
        for (int i = 0; i < 2; i++) {
            const int chunk = i * 256 + tid;
            const int row   = chunk >> 4;
            const int c0    = 128 + (chunk & 15) * 8;
            const int sw    = ((row >> 2) & 3) << 4;
            const int node  = m0 + row;
            if (node <= N_NODES) {
                uint4 v = make_uint4(0, 0, 0, 0);
                if (node < N_NODES)
                    v = *(const uint4*)(Es + row * 256 + (c0 ^ sw));
                *(uint4*)(Sout + (size_t)node * 128 + (c0 - 128)) = v;
            }
        }
    } else {
        // DO=64 (layer 3, R22a): T fp8 cols 0..63 (32x4 chunks of 16 dims,
        // threads 0..127) + S bf16 cols 64..127 (256 chunks, 1/thread).
        unsigned char* T8o = (unsigned char*)Tout;
        if (tid < 128) {
            const int row = tid >> 2;
            const int c0  = (tid & 3) * 16;
            const int sw  = ((row >> 2) & 3) << 4;
            const int node = m0 + row;
            if (node <= N_NODES) {
                uint4 v = make_uint4(0, 0, 0, 0);
                if (node < N_NODES) {
                    const unsigned short* p = Es + row * 128 + (c0 ^ sw);
                    uint4 ha = *(const uint4*)p;
                    uint4 hb = *(const uint4*)(p + 8);
                    v.x = pack4_fp8(LOF(ha.x), HIF(ha.x), LOF(ha.y), HIF(ha.y));
                    v.y = pack4_fp8(LOF(ha.z), HIF(ha.z), LOF(ha.w), HIF(ha.w));
                    v.z = pack4_fp8(LOF(hb.x), HIF(hb.x), LOF(hb.y), HIF(hb.y));
                    v.w = pack4_fp8(LOF(hb.z), HIF(hb.z), LOF(hb.w), HIF(hb.w));
                }
                *(uint4*)(T8o + (size_t)node * 64 + c0) = v;
            }
        }
        {
            const int chunk = tid;               // 256 chunks
            const int row   = chunk >> 3;
            const int c0    = 64 + (chunk & 7) * 8;
            const int sw    = ((row >> 2) & 3) << 4;
            const int node  = m0 + row;
            if (node <= N_NODES) {
                uint4 v = make_uint4(0, 0, 0, 0);
                if (node < N_NODES)
                    v = *(const uint4*)(Es + row * 128 + (c0 ^ sw));
                *(uint4*)(Sout + (size_t)node * 64 + (c0 - 64)) = v;
            }
        }
    }
#undef LOF
#undef HIF
}

// ---------------------------------------------------------------- final aggregate
// R22a: fp8 T3 row = 64B = 4 uint4 -> 4 req/edge. 16 lanes/node =
// 4 dim-quarters (lane bits 0,1) x 4 edge-groups (lane bits 2,3).
// Edge-group merge via shfl_xor(4,8); softmax reduce via shfl_xor(1,2).
__global__ __launch_bounds__(256) void agg_last_kernel(const unsigned char* __restrict__ T8,
                                                       const unsigned short* __restrict__ S,
                                                       const float* __restrict__ br,
                                                       const int* __restrict__ deg,
                                                       const int* __restrict__ esrc,
                                                       float* __restrict__ Fout) {
    const int lane16 = threadIdx.x & 15;
    const int dimq   = lane16 & 3;       // dims dimq*16..+15
    const int g      = lane16 >> 2;      // edge group 0..3
    const int n      = blockIdx.x * 16 + (threadIdx.x >> 4);

    int cnt = deg[n];
    if (cnt > ROW_CAP) cnt = ROW_CAP;
    const int* erow = esrc + (size_t)n * ROW_CAP;
    const uint4* T4 = (const uint4*)T8;  // fp8 row = 4 uint4

    v2f acc[8];
#pragma unroll
    for (int i = 0; i < 8; i++) acc[i] = (v2f)(0.0f);

    for (int o = g * 4; o < cnt; o += 16) {
        int4 i0 = *(const int4*)(erow + o);
        i0.x = (o + 0 < cnt) ? i0.x : N_NODES;
        i0.y = (o + 1 < cnt) ? i0.y : N_NODES;
        i0.z = (o + 2 < cnt) ? i0.z : N_NODES;
        i0.w = (o + 3 < cnt) ? i0.w : N_NODES;
        uint4 q0 = T4[(size_t)i0.x * 4 + dimq];
        uint4 q1 = T4[(size_t)i0.y * 4 + dimq];
        uint4 q2 = T4[(size_t)i0.z * 4 + dimq];
        uint4 q3 = T4[(size_t)i0.w * 4 + dimq];
        addp16(acc, q0); addp16(acc, q1); addp16(acc, q2); addp16(acc, q3);
    }
    // merge the 4 edge groups (lane bits 2,3)
#pragma unroll
    for (int i = 0; i < 8; i++) {
        acc[i].x += __shfl_xor(acc[i].x, 4);
        acc[i].y += __shfl_xor(acc[i].y, 4);
        acc[i].x += __shfl_xor(acc[i].x, 8);
        acc[i].y += __shfl_xor(acc[i].y, 8);
    }

    // + S (bf16 exact) + bias + relu: 16 dims per lane
    uint4 sv0 = ((const uint4*)S)[(size_t)n * 8 + dimq * 2];
    uint4 sv1 = ((const uint4*)S)[(size_t)n * 8 + dimq * 2 + 1];
    addp(acc, sv0); addp(acc + 4, sv1);

    const float4 b0 = ((const float4*)br)[dimq * 4];
    const float4 b1 = ((const float4*)br)[dimq * 4 + 1];
    const float4 b2 = ((const float4*)br)[dimq * 4 + 2];
    const float4 b3 = ((const float4*)br)[dimq * 4 + 3];

    float v[16];
    v[0]  = fmaxf(acc[0].x + b0.x, 0.f); v[1]  = fmaxf(acc[0].y + b0.y, 0.f);
    v[2]  = fmaxf(acc[1].x + b0.z, 0.f); v[3]  = fmaxf(acc[1].y + b0.w, 0.f);
    v[4]  = fmaxf(acc[2].x + b1.x, 0.f); v[5]  = fmaxf(acc[2].y + b1.y, 0.f);
    v[6]  = fmaxf(acc[3].x + b1.z, 0.f); v[7]  = fmaxf(acc[3].y + b1.w, 0.f);
    v[8]  = fmaxf(acc[4].x + b2.x, 0.f); v[9]  = fmaxf(acc[4].y + b2.y, 0.f);
    v[10] = fmaxf(acc[5].x + b2.z, 0.f); v[11] = fmaxf(acc[5].y + b2.w, 0.f);
    v[12] = fmaxf(acc[6].x + b3.x, 0.f); v[13] = fmaxf(acc[6].y + b3.y, 0.f);
    v[14] = fmaxf(acc[7].x + b3.z, 0.f); v[15] = fmaxf(acc[7].y + b3.w, 0.f);

    // log_softmax over 64 dims = 4 dimq lanes (lane bits 0,1)
    float m = v[0];
#pragma unroll
    for (int i = 1; i < 16; i++) m = fmaxf(m, v[i]);
    m = fmaxf(m, __shfl_xor(m, 1));
    m = fmaxf(m, __shfl_xor(m, 2));
    float es = 0.f;
#pragma unroll
    for (int i = 0; i < 16; i++) es += expf(v[i] - m);
    es += __shfl_xor(es, 1);
    es += __shfl_xor(es, 2);
    float lse = m + logf(es);

    if (g == 0) {
#pragma unroll
        for (int k = 0; k < 4; k++) {
            float4 o = make_float4(v[k * 4 + 0] - lse, v[k * 4 + 1] - lse,
                                   v[k * 4 + 2] - lse, v[k * 4 + 3] - lse);
            ((float4*)Fout)[(size_t)n * 16 + dimq * 4 + k] = o;
        }
    }
}

// ---------------------------------------------------------------- launch

extern "C" void kernel_launch(void* const* d_in, const int* in_sizes, int n_in,
                              void* d_out, int out_size, void* d_ws, size_t ws_size,
                              hipStream_t stream) {
    const float* x    = (const float*)d_in[0];
    const int*   eidx = (const int*)d_in[1];   // [2, E] int32
    const float* Wr0  = (const float*)d_in[2];
    const float* br0  = (const float*)d_in[3];
    const float* Ws0  = (const float*)d_in[4];
    const float* Wr1  = (const float*)d_in[5];
    const float* br1  = (const float*)d_in[6];
    const float* Ws1  = (const float*)d_in[7];
    const float* Wr2  = (const float*)d_in[8];
    const float* br2  = (const float*)d_in[9];
    const float* Ws2  = (const float*)d_in[10];
    float* out = (float*)d_out;

    const int* src = eidx;
    const int* dst = eidx + N_EDGES;

    auto align = [](size_t v) { return (v + 255) & ~(size_t)255; };
    char* w = (char*)d_ws;
    int* deg  = (int*)w;  w += align(sizeof(int) * DEG_CAP);
    int* esrc = (int*)w;  w += align(sizeof(int) * (size_t)N_NODES * ROW_CAP);
    unsigned short* Wt0 = (unsigned short*)w;  w += align(2ull * 256 * 128);
    unsigned short* Wt1 = (unsigned short*)w;  w += align(2ull * 256 * 128);
    unsigned short* Wt2 = (unsigned short*)w;  w += align(2ull * 128 * 128);
    void* T_a = (void*)w;                      w += align(2ull * PAD_NODES * 64);  // fp8 128 / fp8 64
    void* T_b = (void*)w;                      w += align(2ull * PAD_NODES * 64);
    unsigned short* S_a = (unsigned short*)w;  w += align(2ull * PAD_NODES * 128);
    unsigned short* S_b = (unsigned short*)w;  w += align(2ull * PAD_NODES * 128);
    (void)ws_size; (void)n_in; (void)in_sizes; (void)out_size;

    // ---- deg zero (async memset) + fused prep/place
    hipMemsetAsync(deg, 0, sizeof(int) * DEG_CAP, stream);
    prep_place_kernel<<<2820, 256, 0, stream>>>(
        src, dst, deg, esrc, Wr0, Ws0, Wr1, Ws1, Wr2, Ws2, Wt0, Wt1, Wt2);

    // ---- layer 1: mm only (fp32 x -> T_a fp8, S_a)
    mmf_kernel<128, false, true><<<PAD_NODES / 32, 256, 0, stream>>>(
        x, nullptr, nullptr, nullptr, nullptr, Wt0, T_a, S_a);

    // ---- layer 2: agg(L1) prologue + mm (T_a,S_a -> T_b fp8, S_b)
    mmf_kernel<128, true, false><<<PAD_NODES / 32, 256, 0, stream>>>(
        T_a, S_a, br0, deg, esrc, Wt1, T_b, S_b);

    // ---- layer 3: agg(L2) prologue + mm (T_b,S_b -> T_a fp8[64], S_a[64])
    mmf_kernel<64, true, false><<<PAD_NODES / 32, 256, 0, stream>>>(
        T_b, S_b, br1, deg, esrc, Wt2, T_a, S_a);

    // ---- final aggregate + log_softmax (fp8 T3, 4 req/edge)
    agg_last_kernel<<<N_NODES / 16, 256, 0, stream>>>(
        (const unsigned char*)T_a, S_a, br2, deg, esrc, out);
}